// Round 13
// baseline (401.866 us; speedup 1.0000x reference)
//
#include <hip/hip_runtime.h>

typedef __attribute__((ext_vector_type(8))) short bf16x8;
typedef __attribute__((ext_vector_type(4))) float f32x4;
typedef __attribute__((ext_vector_type(2))) float f32x2;

#define L2E 1.4426950408889634f
#define S6A (0.6f * L2E)

static __device__ __forceinline__ float wsum64(float v) {
#pragma unroll
    for (int off = 32; off >= 1; off >>= 1) v += __shfl_xor(v, off, 64);
    return v;
}
static __device__ __forceinline__ float wmax64(float v) {
#pragma unroll
    for (int off = 32; off >= 1; off >>= 1) v = fmaxf(v, __shfl_xor(v, off, 64));
    return v;
}

static __device__ __forceinline__ unsigned short bf16r(float a) {
    unsigned int u = __float_as_uint(a);
    return (unsigned short)((u + 0x7FFFu + ((u >> 16) & 1u)) >> 16);
}
static __device__ __forceinline__ unsigned int bf16pack(float a, float b) {
    unsigned int ua = __float_as_uint(a);
    ua = (ua + 0x7FFFu + ((ua >> 16) & 1u)) >> 16;
    unsigned int ub = __float_as_uint(b);
    ub = (ub + 0x7FFFu + ((ub >> 16) & 1u)) & 0xFFFF0000u;
    return ua | ub;
}
static __device__ __forceinline__ float rflf(float v) {
    return __int_as_float(__builtin_amdgcn_readfirstlane(__float_as_int(v)));
}
static __device__ __forceinline__ f32x2 sp2(float v) {
    f32x2 r; r.x = v; r.y = v; return r;
}

// ---- fp8 e4m3 (HW cvt if available) ----
#if __has_builtin(__builtin_amdgcn_cvt_pk_f32_fp8) && __has_builtin(__builtin_amdgcn_cvt_pk_fp8_f32)
static __device__ __forceinline__ void fp8dec(unsigned int u, f32x2& lo, f32x2& hi) {
    lo = __builtin_amdgcn_cvt_pk_f32_fp8((int)u, false);
    hi = __builtin_amdgcn_cvt_pk_f32_fp8((int)u, true);
}
static __device__ __forceinline__ unsigned int fp8pack4(float a, float b, float c, float d) {
    int u = 0;
    u = __builtin_amdgcn_cvt_pk_fp8_f32(a, b, u, false);
    u = __builtin_amdgcn_cvt_pk_fp8_f32(c, d, u, true);
    return (unsigned int)u;
}
#else
static __device__ __forceinline__ float fp8_1(unsigned int b) {
    return __uint_as_float(((b & 0x80u) << 24) | ((b & 0x7Fu) << 20)) * 0x1p+120f;
}
static __device__ __forceinline__ void fp8dec(unsigned int u, f32x2& lo, f32x2& hi) {
    lo.x = fp8_1(u & 255u); lo.y = fp8_1((u >> 8) & 255u);
    hi.x = fp8_1((u >> 16) & 255u); hi.y = fp8_1(u >> 24);
}
static __device__ __forceinline__ unsigned int fp8enc1(float v) {
    unsigned int s = (__float_as_uint(v) >> 24) & 0x80u;
    float a = fminf(fabsf(v), 448.f);
    unsigned int b;
    if (a < 0.015625f) {
        b = (unsigned int)__float2int_rn(a * 512.f);
    } else {
        unsigned int ua = __float_as_uint(a);
        ua += 0x000FFFFFu + ((ua >> 20) & 1u);
        unsigned int e = ua >> 23;
        if (e > 135u) b = 0x7Eu;
        else b = ((e - 120u) << 3) | ((ua >> 20) & 7u);
    }
    return s | b;
}
static __device__ __forceinline__ unsigned int fp8pack4(float a, float b, float c, float d) {
    return fp8enc1(a) | (fp8enc1(b) << 8) | (fp8enc1(c) << 16) | (fp8enc1(d) << 24);
}
#endif

// packed abs-dot: sum av4_i * |xs_i + pre_i| over 4 dims (2x f32x2)
static __device__ __forceinline__ float adot_pk(f32x2 xlo, f32x2 xhi, f32x2 plo, f32x2 phi,
                                                f32x2 alo, f32x2 ahi) {
    f32x2 mlo = xlo + plo;
    f32x2 mhi = xhi + phi;
    mlo = __builtin_elementwise_max(mlo, -mlo);
    mhi = __builtin_elementwise_max(mhi, -mhi);
    f32x2 qp = mlo * alo + mhi * ahi;
    return qp.x + qp.y;
}

// permutation: natural col j -> MFMA-native storage slot
static __device__ __forceinline__ int permS(int j) {
    int nb = j >> 7, r = j & 127;
    return nb * 128 + (r & 15) * 8 + (r >> 4);
}
static __device__ __forceinline__ int permK(int s) {
    int nb = s >> 7, r = s & 127;
    return nb * 128 + (r & 7) * 16 + (r >> 3);
}

// ---------- fused: edge histogram + weight conversion + flow tables ----------
__global__ void k_edges_prep(const int* __restrict__ ei, const int* __restrict__ ea,
        int* __restrict__ cntF, int* __restrict__ cnt3, int E, int EB,
        const float* __restrict__ pos_table, const float* __restrict__ pos_W,
        const float* __restrict__ pos_b, const float* __restrict__ flow_emb,
        const float* __restrict__ We1, const float* __restrict__ We2,
        const float* __restrict__ att1, const float* __restrict__ bias1,
        float* __restrict__ eaW1p, float* __restrict__ att1p, float* __restrict__ bias1p,
        float* __restrict__ eaW2, float* __restrict__ delta, float* __restrict__ poscS,
        const float* __restrict__ Wl1, const float* __restrict__ Wr1,
        const float* __restrict__ Wl2, const float* __restrict__ Wr2,
        unsigned short* __restrict__ Bt1, unsigned short* __restrict__ Bt2) {
    __shared__ int sh3[3];
    __shared__ float posc[128];
    __shared__ float red4[768];
    int bid = blockIdx.x, t = threadIdx.x;
    if (bid < EB) {
        if (t < 3) sh3[t] = 0;
        __syncthreads();
        int e = bid * 256 + t;
        if (e < E) {
            int dd = ei[E + e];
            int f = ((const int2*)ea)[e].x;
            f = f < 0 ? 0 : (f > 2 ? 2 : f);
            atomicAdd(&cntF[dd * 3 + f], 1);
            atomicAdd(&sh3[f], 1);
        }
        __syncthreads();
        if (t < 3) atomicAdd(&cnt3[t], sh3[t]);
        return;
    }
    if (bid < EB + 320) {
        int i = (bid - EB) * 256 + t;
        if (i < 512 * 128) {
            int nn = i >> 7, k = i & 127;
            float v = (nn < 256) ? Wl1[(size_t)k * 256 + nn] : Wr1[(size_t)k * 256 + nn - 256];
            Bt1[i] = bf16r(v);
        } else {
            int j = i - 512 * 128;
            if (j < 64 * 256) {
                int nn = j >> 8, s = j & 255;
                int kk = permK(s);
                float v = (nn < 32) ? Wl2[(size_t)kk * 32 + nn] : Wr2[(size_t)kk * 32 + nn - 32];
                Bt2[j] = bf16r(v);
            }
        }
        return;
    }
    // tables block (cnt3-independent)
    if (t < 128) {
        const float* row = pos_table + 5120 * 128;
        float a = pos_b[t];
        for (int k = 0; k < 128; ++k) a += row[k] * pos_W[k * 128 + t];
        posc[t] = a;
        poscS[t] = a;
    }
    __syncthreads();
    {
        int j = t;
        float a0 = 0.f, a1 = 0.f, a2 = 0.f;
        for (int k = 0; k < 128; ++k) {
            float w = We1[k * 256 + j];
            float pc = posc[k];
            a0 += (flow_emb[k] + pc) * w;
            a1 += (flow_emb[128 + k] + pc) * w;
            a2 += (flow_emb[256 + k] + pc) * w;
        }
        int s = permS(j);
        eaW1p[s] = a0; eaW1p[256 + s] = a1; eaW1p[512 + s] = a2;
        att1p[s] = att1[j];
        bias1p[s] = bias1[j];
        float avj = att1[j];
        red4[t] = avj * a0; red4[256 + t] = avj * a1; red4[512 + t] = avj * a2;
    }
    __syncthreads();
    if (t < 3) {
        float s = 0.f;
        const float* rr = red4 + t * 256;
        for (int k = 0; k < 256; ++k) s += rr[k];
        delta[t] = s * S6A;
    }
    if (t < 32) {
        int j = t;
        float a0 = 0.f, a1 = 0.f, a2 = 0.f;
        for (int k = 0; k < 128; ++k) {
            float w = We2[k * 32 + j];
            float pc = posc[k];
            a0 += (flow_emb[k] + pc) * w;
            a1 += (flow_emb[128 + k] + pc) * w;
            a2 += (flow_emb[256 + k] + pc) * w;
        }
        eaW2[j] = a0; eaW2[32 + j] = a1; eaW2[64 + j] = a2;
    }
}

// ---------- scan blocks + loop-attr (cnt3-dependent) tables ----------
__global__ __launch_bounds__(256) void k_scan_block(const int* __restrict__ cnt,
        int* __restrict__ rowptr, int* __restrict__ bsum, int n, int nb,
        const int* __restrict__ cnt3, const float* __restrict__ poscS,
        const float* __restrict__ flow_emb, const float* __restrict__ We1,
        const float* __restrict__ We2, const float* __restrict__ att1,
        float* __restrict__ loopW1p, float* __restrict__ loopW2,
        float* __restrict__ delta, int E) {
    __shared__ int sh[256];
    __shared__ float lv[128];
    __shared__ float red[256];
    int b = blockIdx.x, t = threadIdx.x;
    if (b == nb) {  // loop-attr tables
        if (t < 128) {
            float invE = 1.0f / (float)E;
            lv[t] = ((float)cnt3[0] * flow_emb[t] + (float)cnt3[1] * flow_emb[128 + t] +
                     (float)cnt3[2] * flow_emb[256 + t]) * invE + poscS[t];
        }
        __syncthreads();
        {
            int j = t;
            float al = 0.f;
            for (int k = 0; k < 128; ++k) al += lv[k] * We1[k * 256 + j];
            loopW1p[permS(j)] = al;
            red[t] = att1[j] * al;
        }
        __syncthreads();
        if (t == 0) {
            float s = 0.f;
            for (int k = 0; k < 256; ++k) s += red[k];
            delta[3] = s * S6A;
        }
        if (t < 32) {
            float al = 0.f;
            for (int k = 0; k < 128; ++k) al += lv[k] * We2[k * 32 + t];
            loopW2[t] = al;
        }
        return;
    }
    int base = b * 1024 + t * 4;
    int v0 = base + 0 < n ? cnt[base + 0] : 0;
    int v1 = base + 1 < n ? cnt[base + 1] : 0;
    int v2 = base + 2 < n ? cnt[base + 2] : 0;
    int v3 = base + 3 < n ? cnt[base + 3] : 0;
    int tot = v0 + v1 + v2 + v3;
    sh[t] = tot;
    __syncthreads();
    for (int off = 1; off < 256; off <<= 1) {
        int x = (t >= off) ? sh[t - off] : 0;
        __syncthreads();
        sh[t] += x;
        __syncthreads();
    }
    int excl = (t > 0) ? sh[t - 1] : 0;
    if (base + 0 < n) rowptr[base + 0] = excl;
    if (base + 1 < n) rowptr[base + 1] = excl + v0;
    if (base + 2 < n) rowptr[base + 2] = excl + v0 + v1;
    if (base + 3 < n) rowptr[base + 3] = excl + v0 + v1 + v2;
    if (t == 255) bsum[b] = sh[255];
}

// fused lookback: adds prefix of bsum; block 0 also writes rowptr[n] = total
__global__ __launch_bounds__(256) void k_scan_add(int* __restrict__ rowptr,
        const int* __restrict__ bsum, int* __restrict__ wptr, int n, int nb) {
    __shared__ int red[256];
    int b = blockIdx.x, t = threadIdx.x;
    int lim = b >> 2;
    int local = 0;
    for (int k = t; k < lim; k += 256) local += bsum[k];
    red[t] = local;
    __syncthreads();
    for (int s = 128; s > 0; s >>= 1) {
        if (t < s) red[t] += red[t + s];
        __syncthreads();
    }
    int P = red[0];
    if (b == 0) {
        P = 0;
        int tot = 0;
        for (int k = t; k < nb; k += 256) tot += bsum[k];
        __syncthreads();
        red[t] = tot;
        __syncthreads();
        for (int s = 128; s > 0; s >>= 1) {
            if (t < s) red[t] += red[t + s];
            __syncthreads();
        }
        if (t == 0) rowptr[n] = red[0];
    }
    int i = b * 256 + t;
    if (i < n) {
        int v = rowptr[i] + P;
        rowptr[i] = v;
        wptr[i] = v;
    }
}

// ---------- scatter (standalone, no LDS -> full occupancy) ----------
__global__ void k_scatter(const int* __restrict__ ei, const int* __restrict__ ea,
                          int* __restrict__ wptr, int* __restrict__ packed, int E) {
    int e = blockIdx.x * blockDim.x + threadIdx.x;
    if (e >= E) return;
    int s = ei[e], dd = ei[E + e];
    int f = ((const int2*)ea)[e].x;
    f = f < 0 ? 0 : (f > 2 ? 2 : f);
    int p = atomicAdd(&wptr[dd * 3 + f], 1);
    packed[p] = s | (f << 16);
}

// ---------- GEMM 1 (MFMA) + alpha: xl8[N][256] fp8 perm, xrp[N][256] bf16 perm ----------
__global__ __launch_bounds__(256) void k_gemm1(const int* __restrict__ x,
        const float* __restrict__ text_emb, const float* __restrict__ type_emb,
        const unsigned short* __restrict__ Bt,
        const float* __restrict__ bl, const float* __restrict__ br,
        const float* __restrict__ att, float* __restrict__ alpha,
        unsigned char* __restrict__ xl8, unsigned short* __restrict__ xrp, int n) {
    __shared__ unsigned short Ash[64][136];
    __shared__ unsigned short Bsh[128][136];
    int t = threadIdx.x;
    int node0 = blockIdx.x * 64;
    for (int i = t; i < 64 * 128; i += 256) {
        int r = i >> 7, cc = i & 127;
        int nd = node0 + r;
        float v = 0.f;
        if (nd < n)
            v = (cc < 64) ? text_emb[(size_t)x[nd * 2] * 64 + cc]
                          : type_emb[(size_t)x[nd * 2 + 1] * 64 + (cc - 64)];
        Ash[r][cc] = bf16r(v);
    }
    int wave = t >> 6, lane = t & 63;
    int m = lane & 15, q = lane >> 4;
    for (int nb = 0; nb < 4; ++nb) {
        __syncthreads();
        for (int i = t; i < 128 * 16; i += 256) {
            int r = i >> 4, cs = i & 15;
            uint4 v = ((const uint4*)(Bt + (size_t)(nb * 128 + r) * 128))[cs];
            *(uint4*)&Bsh[r][cs * 8] = v;
        }
        __syncthreads();
        f32x4 acc[8];
#pragma unroll
        for (int nt = 0; nt < 8; ++nt) acc[nt] = (f32x4){0.f, 0.f, 0.f, 0.f};
#pragma unroll
        for (int k = 0; k < 128; k += 32) {
            bf16x8 a = *(const bf16x8*)&Ash[wave * 16 + m][k + q * 8];
#pragma unroll
            for (int nt = 0; nt < 8; ++nt) {
                bf16x8 b = *(const bf16x8*)&Bsh[nt * 16 + m][k + q * 8];
                acc[nt] = __builtin_amdgcn_mfma_f32_16x16x32_bf16(a, b, acc[nt], 0, 0, 0);
            }
        }
        float bv[8];
#pragma unroll
        for (int nt = 0; nt < 8; ++nt) {
            int ng = nb * 128 + nt * 16 + m;
            bv[nt] = (nb < 2) ? bl[ng] : br[ng - 256];
        }
#pragma unroll
        for (int r = 0; r < 4; ++r) {
            int node = node0 + wave * 16 + q * 4 + r;
            if (node >= n) continue;
            if (nb < 2) {
                unsigned int u0 = fp8pack4(acc[0][r] + bv[0], acc[1][r] + bv[1],
                                           acc[2][r] + bv[2], acc[3][r] + bv[3]);
                unsigned int u1 = fp8pack4(acc[4][r] + bv[4], acc[5][r] + bv[5],
                                           acc[6][r] + bv[6], acc[7][r] + bv[7]);
                *(uint2*)(xl8 + (size_t)node * 256 + nb * 128 + m * 8) = make_uint2(u0, u1);
            } else {
                uint4 o;
                o.x = bf16pack(acc[0][r] + bv[0], acc[1][r] + bv[1]);
                o.y = bf16pack(acc[2][r] + bv[2], acc[3][r] + bv[3]);
                o.z = bf16pack(acc[4][r] + bv[4], acc[5][r] + bv[5]);
                o.w = bf16pack(acc[6][r] + bv[6], acc[7][r] + bv[7]);
                *(uint4*)(xrp + (size_t)node * 256 + (nb - 2) * 128 + m * 8) = o;
            }
        }
        if (nb < 2) {
            float p0 = 0.f, p1 = 0.f, p2 = 0.f, p3 = 0.f;
#pragma unroll
            for (int nt = 0; nt < 8; ++nt) {
                int ng = nb * 128 + nt * 16 + m;
                float avv = att[ng];
                p0 = fmaf(avv, acc[nt][0] + bv[nt], p0);
                p1 = fmaf(avv, acc[nt][1] + bv[nt], p1);
                p2 = fmaf(avv, acc[nt][2] + bv[nt], p2);
                p3 = fmaf(avv, acc[nt][3] + bv[nt], p3);
            }
#pragma unroll
            for (int off = 1; off <= 8; off <<= 1) {
                p0 += __shfl_xor(p0, off, 64);
                p1 += __shfl_xor(p1, off, 64);
                p2 += __shfl_xor(p2, off, 64);
                p3 += __shfl_xor(p3, off, 64);
            }
            if (m == 0) {
                int nodeb = node0 + wave * 16 + q * 4;
                if (nodeb + 0 < n) atomicAdd(&alpha[nodeb + 0], p0 * S6A);
                if (nodeb + 1 < n) atomicAdd(&alpha[nodeb + 1], p1 * S6A);
                if (nodeb + 2 < n) atomicAdd(&alpha[nodeb + 2], p2 * S6A);
                if (nodeb + 3 < n) atomicAdd(&alpha[nodeb + 3], p3 * S6A);
            }
        }
    }
}

// ---------- GEMM 2 (MFMA) ----------
__global__ __launch_bounds__(256) void k_gemm2(const unsigned short* __restrict__ h2b,
        const unsigned short* __restrict__ Bt,
        const float* __restrict__ bl, const float* __restrict__ br,
        unsigned short* __restrict__ xc, int n) {
    __shared__ unsigned short Ash[32][264];
    __shared__ unsigned short Bsh[64][264];
    int t = threadIdx.x;
    int node0 = blockIdx.x * 32;
    for (int i = t; i < 32 * 32; i += 256) {
        int r = i >> 5, cs = i & 31;
        int nd = node0 + r;
        uint4 v = make_uint4(0u, 0u, 0u, 0u);
        if (nd < n) v = ((const uint4*)(h2b + (size_t)nd * 256))[cs];
        *(uint4*)&Ash[r][cs * 8] = v;
    }
    for (int i = t; i < 64 * 32; i += 256) {
        int r = i >> 5, cs = i & 31;
        uint4 v = ((const uint4*)(Bt + (size_t)r * 256))[cs];
        *(uint4*)&Bsh[r][cs * 8] = v;
    }
    __syncthreads();
    int wave = t >> 6, lane = t & 63;
    int m = lane & 15, q = lane >> 4;
    int mrow = (wave >> 1) * 16;
    int nh   = (wave & 1) * 32;
    f32x4 acc[2];
    acc[0] = (f32x4){0.f, 0.f, 0.f, 0.f};
    acc[1] = (f32x4){0.f, 0.f, 0.f, 0.f};
#pragma unroll
    for (int k = 0; k < 256; k += 32) {
        bf16x8 a = *(const bf16x8*)&Ash[mrow + m][k + q * 8];
#pragma unroll
        for (int nt = 0; nt < 2; ++nt) {
            bf16x8 b = *(const bf16x8*)&Bsh[nh + nt * 16 + m][k + q * 8];
            acc[nt] = __builtin_amdgcn_mfma_f32_16x16x32_bf16(a, b, acc[nt], 0, 0, 0);
        }
    }
#pragma unroll
    for (int r = 0; r < 4; ++r) {
        int node = node0 + mrow + q * 4 + r;
        if (node < n) {
#pragma unroll
            for (int nt = 0; nt < 2; ++nt) {
                int ng = nh + nt * 16 + m;
                float bvv = (ng < 32) ? bl[ng] : br[ng - 32];
                xc[(size_t)node * 64 + ng] = bf16r(acc[nt][r] + bvv);
            }
        }
    }
}

// ---------- GAT layer 1: wave/dst, fp8 gathers, 8 edges in flight ----------
__global__ __launch_bounds__(256) void k_gat256(const unsigned char* __restrict__ xl8,
        const unsigned short* __restrict__ xrp,
        const int* __restrict__ rowptrF, const int* __restrict__ packed,
        const float* __restrict__ eaWp, const float* __restrict__ loopWp,
        const float* __restrict__ attp, const float* __restrict__ biasp,
        const float* __restrict__ alpha, const float* __restrict__ delta,
        unsigned short* __restrict__ h2b, int n) {
    int wid = (blockIdx.x * blockDim.x + threadIdx.x) >> 6;
    if (wid >= n) return;
    int d = __builtin_amdgcn_readfirstlane(wid);
    int lane = threadIdx.x & 63;
    int c = lane * 4;
    const float S4 = 0.4f * L2E;
    f32x2 xldL, xldH;
    fp8dec(*(const unsigned int*)(xl8 + (size_t)d * 256 + c), xldL, xldH);
    uint2 uxr = ((const uint2*)(xrp + (size_t)d * 256))[lane];
    f32x2 xrdL, xrdH;
    xrdL.x = __uint_as_float(uxr.x << 16); xrdL.y = __uint_as_float(uxr.x & 0xFFFF0000u);
    xrdH.x = __uint_as_float(uxr.y << 16); xrdH.y = __uint_as_float(uxr.y & 0xFFFF0000u);
    f32x2 avL = *(const f32x2*)(attp + c), avH = *(const f32x2*)(attp + c + 2);
    f32x2 a4L = avL * sp2(S4), a4H = avH * sp2(S4);
    f32x2 gp = avL * xrdL + avH * xrdH;
    float gd = rflf(wsum64(gp.x + gp.y) * S6A);
    float ab0 = gd + delta[0], ab1 = gd + delta[1], ab2 = gd + delta[2];
    float ab3 = gd + delta[3];
    float alphad = alpha[d];
    f32x2 r0L = *(const f32x2*)(eaWp + c) + xrdL;
    f32x2 r0H = *(const f32x2*)(eaWp + c + 2) + xrdH;
    f32x2 r1L = *(const f32x2*)(eaWp + 256 + c) + xrdL;
    f32x2 r1H = *(const f32x2*)(eaWp + 256 + c + 2) + xrdH;
    f32x2 r2L = *(const f32x2*)(eaWp + 512 + c) + xrdL;
    f32x2 r2H = *(const f32x2*)(eaWp + 512 + c + 2) + xrdH;
    f32x2 lwL = *(const f32x2*)(loopWp + c) + xrdL;
    f32x2 lwH = *(const f32x2*)(loopWp + c + 2) + xrdH;
    int jj = lane & 15;
    int a0i = jj << 2, a1i = (jj + 16) << 2, a2i = (jj + 32) << 2, a3i = (jj + 48) << 2;
    bool bq0 = (lane & 16) != 0, bq1 = (lane & 32) != 0;
    float den;
    f32x2 accL, accH;
    {
        float q = wsum64(adot_pk(xldL, xldH, lwL, lwH, a4L, a4H)) + alphad + ab3;
        float wself = exp2f(q);
        den = wself;
        accL = xldL * sp2(wself);
        accH = xldH * sp2(wself);
    }
    int p = rowptrF[d * 3], p1 = rowptrF[d * 3 + 3];
    // ---- 8 edges in flight ----
    for (; p + 8 <= p1; p += 8) {
        int pk0 = packed[p],     pk1 = packed[p + 1];
        int pk2 = packed[p + 2], pk3 = packed[p + 3];
        int pk4 = packed[p + 4], pk5 = packed[p + 5];
        int pk6 = packed[p + 6], pk7 = packed[p + 7];
        int s0 = pk0 & 0xFFFF, s1 = pk1 & 0xFFFF, s2 = pk2 & 0xFFFF, s3 = pk3 & 0xFFFF;
        int s4 = pk4 & 0xFFFF, s5 = pk5 & 0xFFFF, s6 = pk6 & 0xFFFF, s7 = pk7 & 0xFFFF;
        int f0 = pk0 >> 16, f1 = pk1 >> 16, f2 = pk2 >> 16, f3 = pk3 >> 16;
        int f4 = pk4 >> 16, f5 = pk5 >> 16, f6 = pk6 >> 16, f7 = pk7 >> 16;
        unsigned int g0 = *(const unsigned int*)(xl8 + (size_t)s0 * 256 + c);
        unsigned int g1 = *(const unsigned int*)(xl8 + (size_t)s1 * 256 + c);
        unsigned int g2 = *(const unsigned int*)(xl8 + (size_t)s2 * 256 + c);
        unsigned int g3 = *(const unsigned int*)(xl8 + (size_t)s3 * 256 + c);
        unsigned int g4 = *(const unsigned int*)(xl8 + (size_t)s4 * 256 + c);
        unsigned int g5 = *(const unsigned int*)(xl8 + (size_t)s5 * 256 + c);
        unsigned int g6 = *(const unsigned int*)(xl8 + (size_t)s6 * 256 + c);
        unsigned int g7 = *(const unsigned int*)(xl8 + (size_t)s7 * 256 + c);
        float sc0 = alpha[s0] + ((f0 == 0) ? ab0 : ((f0 == 1) ? ab1 : ab2));
        float sc1 = alpha[s1] + ((f1 == 0) ? ab0 : ((f1 == 1) ? ab1 : ab2));
        float sc2 = alpha[s2] + ((f2 == 0) ? ab0 : ((f2 == 1) ? ab1 : ab2));
        float sc3 = alpha[s3] + ((f3 == 0) ? ab0 : ((f3 == 1) ? ab1 : ab2));
        float sc4 = alpha[s4] + ((f4 == 0) ? ab0 : ((f4 == 1) ? ab1 : ab2));
        float sc5 = alpha[s5] + ((f5 == 0) ? ab0 : ((f5 == 1) ? ab1 : ab2));
        float sc6 = alpha[s6] + ((f6 == 0) ? ab0 : ((f6 == 1) ? ab1 : ab2));
        float sc7 = alpha[s7] + ((f7 == 0) ? ab0 : ((f7 == 1) ? ab1 : ab2));
        f32x2 x0L, x0H, x1L, x1H, x2L, x2H, x3L, x3H;
        f32x2 x4L, x4H, x5L, x5H, x6L, x6H, x7L, x7H;
        fp8dec(g0, x0L, x0H); fp8dec(g1, x1L, x1H);
        fp8dec(g2, x2L, x2H); fp8dec(g3, x3L, x3H);
        fp8dec(g4, x4L, x4H); fp8dec(g5, x5L, x5H);
        fp8dec(g6, x6L, x6H); fp8dec(g7, x7L, x7H);
        float q0, q1, q2, q3, q4, q5, q6, q7;
        if (f0 == f7) {  // uniform-flow batch (common: flow-sorted)
            f32x2 pL = (f0 == 0) ? r0L : ((f0 == 1) ? r1L : r2L);
            f32x2 pH = (f0 == 0) ? r0H : ((f0 == 1) ? r1H : r2H);
            q0 = adot_pk(x0L, x0H, pL, pH, a4L, a4H);
            q1 = adot_pk(x1L, x1H, pL, pH, a4L, a4H);
            q2 = adot_pk(x2L, x2H, pL, pH, a4L, a4H);
            q3 = adot_pk(x3L, x3H, pL, pH, a4L, a4H);
            q4 = adot_pk(x4L, x4H, pL, pH, a4L, a4H);
            q5 = adot_pk(x5L, x5H, pL, pH, a4L, a4H);
            q6 = adot_pk(x6L, x6H, pL, pH, a4L, a4H);
            q7 = adot_pk(x7L, x7H, pL, pH, a4L, a4H);
        } else {
            f32x2 pL, pH;
#define SELP(ff) pL = ((ff) == 0) ? r0L : (((ff) == 1) ? r1L : r2L); \
                 pH = ((ff) == 0) ? r0H : (((ff) == 1) ? r1H : r2H)
            SELP(f0); q0 = adot_pk(x0L, x0H, pL, pH, a4L, a4H);
            SELP(f1); q1 = adot_pk(x1L, x1H, pL, pH, a4L, a4H);
            SELP(f2); q2 = adot_pk(x2L, x2H, pL, pH, a4L, a4H);
            SELP(f3); q3 = adot_pk(x3L, x3H, pL, pH, a4L, a4H);
            SELP(f4); q4 = adot_pk(x4L, x4H, pL, pH, a4L, a4H);
            SELP(f5); q5 = adot_pk(x5L, x5H, pL, pH, a4L, a4H);
            SELP(f6); q6 = adot_pk(x6L, x6H, pL, pH, a4L, a4H);
            SELP(f7); q7 = adot_pk(x7L, x7H, pL, pH, a4L, a4H);
#undef SELP
        }
        // packed reduction batch A (edges 0-3) and B (edges 4-7)
        q0 += __shfl_xor(q0, 16, 64); q1 += __shfl_xor(q1, 16, 64);
        q2 += __shfl_xor(q2, 16, 64); q3 += __shfl_xor(q3, 16, 64);
        q4 += __shfl_xor(q4, 16, 64); q5 += __shfl_xor(q5, 16, 64);
        q6 += __shfl_xor(q6, 16, 64); q7 += __shfl_xor(q7, 16, 64);
        q0 += __shfl_xor(q0, 32, 64); q1 += __shfl_xor(q1, 32, 64);
        q2 += __shfl_xor(q2, 32, 64); q3 += __shfl_xor(q3, 32, 64);
        q4 += __shfl_xor(q4, 32, 64); q5 += __shfl_xor(q5, 32, 64);
        q6 += __shfl_xor(q6, 32, 64); q7 += __shfl_xor(q7, 32, 64);
        float rA01 = bq0 ? q1 : q0, rA23 = bq0 ? q3 : q2;
        float rrA = bq1 ? rA23 : rA01;
        float rB01 = bq0 ? q5 : q4, rB23 = bq0 ? q7 : q6;
        float rrB = bq1 ? rB23 : rB01;
        rrA += __shfl_xor(rrA, 1, 64); rrB += __shfl_xor(rrB, 1, 64);
        rrA += __shfl_xor(rrA, 2, 64); rrB += __shfl_xor(rrB, 2, 64);
        rrA += __shfl_xor(rrA, 4, 64); rrB += __shfl_xor(rrB, 4, 64);
        rrA += __shfl_xor(rrA, 8, 64); rrB += __shfl_xor(rrB, 8, 64);
        float sA01 = bq0 ? sc1 : sc0, sA23 = bq0 ? sc3 : sc2;
        float scvA = bq1 ? sA23 : sA01;
        float sB01 = bq0 ? sc5 : sc4, sB23 = bq0 ? sc7 : sc6;
        float scvB = bq1 ? sB23 : sB01;
        float wA = exp2f(rrA + scvA);
        float wB = exp2f(rrB + scvB);
        int wiA = __float_as_int(wA), wiB = __float_as_int(wB);
        float w0 = __int_as_float(__builtin_amdgcn_ds_bpermute(a0i, wiA));
        float w1 = __int_as_float(__builtin_amdgcn_ds_bpermute(a1i, wiA));
        float w2 = __int_as_float(__builtin_amdgcn_ds_bpermute(a2i, wiA));
        float w3 = __int_as_float(__builtin_amdgcn_ds_bpermute(a3i, wiA));
        float w4 = __int_as_float(__builtin_amdgcn_ds_bpermute(a0i, wiB));
        float w5 = __int_as_float(__builtin_amdgcn_ds_bpermute(a1i, wiB));
        float w6 = __int_as_float(__builtin_amdgcn_ds_bpermute(a2i, wiB));
        float w7 = __int_as_float(__builtin_amdgcn_ds_bpermute(a3i, wiB));
        den += ((w0 + w1) + (w2 + w3)) + ((w4 + w5) + (w6 + w7));
        accL += x0L * sp2(w0) + x1L * sp2(w1) + x2L * sp2(w2) + x3L * sp2(w3);
        accH += x0H * sp2(w0) + x1H * sp2(w1) + x2H * sp2(w2) + x3H * sp2(w3);
        accL += x4L * sp2(w4) + x5L * sp2(w5) + x6L * sp2(w6) + x7L * sp2(w7);
        accH += x4H * sp2(w4) + x5H * sp2(w5) + x6H * sp2(w6) + x7H * sp2(w7);
    }
    // ---- 4-edge batch ----
    for (; p + 4 <= p1; p += 4) {
        int pk0 = packed[p],     pk1 = packed[p + 1];
        int pk2 = packed[p + 2], pk3 = packed[p + 3];
        int s0 = pk0 & 0xFFFF, s1 = pk1 & 0xFFFF;
        int s2 = pk2 & 0xFFFF, s3 = pk3 & 0xFFFF;
        int f0 = pk0 >> 16, f1 = pk1 >> 16, f2 = pk2 >> 16, f3 = pk3 >> 16;
        unsigned int g0 = *(const unsigned int*)(xl8 + (size_t)s0 * 256 + c);
        unsigned int g1 = *(const unsigned int*)(xl8 + (size_t)s1 * 256 + c);
        unsigned int g2 = *(const unsigned int*)(xl8 + (size_t)s2 * 256 + c);
        unsigned int g3 = *(const unsigned int*)(xl8 + (size_t)s3 * 256 + c);
        float sc0 = alpha[s0] + ((f0 == 0) ? ab0 : ((f0 == 1) ? ab1 : ab2));
        float sc1 = alpha[s1] + ((f1 == 0) ? ab0 : ((f1 == 1) ? ab1 : ab2));
        float sc2 = alpha[s2] + ((f2 == 0) ? ab0 : ((f2 == 1) ? ab1 : ab2));
        float sc3 = alpha[s3] + ((f3 == 0) ? ab0 : ((f3 == 1) ? ab1 : ab2));
        f32x2 x0L, x0H, x1L, x1H, x2L, x2H, x3L, x3H;
        fp8dec(g0, x0L, x0H); fp8dec(g1, x1L, x1H);
        fp8dec(g2, x2L, x2H); fp8dec(g3, x3L, x3H);
        float q0, q1, q2, q3;
        {
            f32x2 pL, pH;
#define SELP(ff) pL = ((ff) == 0) ? r0L : (((ff) == 1) ? r1L : r2L); \
                 pH = ((ff) == 0) ? r0H : (((ff) == 1) ? r1H : r2H)
            SELP(f0); q0 = adot_pk(x0L, x0H, pL, pH, a4L, a4H);
            SELP(f1); q1 = adot_pk(x1L, x1H, pL, pH, a4L, a4H);
            SELP(f2); q2 = adot_pk(x2L, x2H, pL, pH, a4L, a4H);
            SELP(f3); q3 = adot_pk(x3L, x3H, pL, pH, a4L, a4H);
#undef SELP
        }
        q0 += __shfl_xor(q0, 16, 64); q1 += __shfl_xor(q1, 16, 64);
        q2 += __shfl_xor(q2, 16, 64); q3 += __shfl_xor(q3, 16, 64);
        q0 += __shfl_xor(q0, 32, 64); q1 += __shfl_xor(q1, 32, 64);
        q2 += __shfl_xor(q2, 32, 64); q3 += __shfl_xor(q3, 32, 64);
        float r01 = bq0 ? q1 : q0, r23 = bq0 ? q3 : q2;
        float rr = bq1 ? r23 : r01;
        rr += __shfl_xor(rr, 1, 64); rr += __shfl_xor(rr, 2, 64);
        rr += __shfl_xor(rr, 4, 64); rr += __shfl_xor(rr, 8, 64);
        float s01 = bq0 ? sc1 : sc0, s23 = bq0 ? sc3 : sc2;
        float scv = bq1 ? s23 : s01;
        float w = exp2f(rr + scv);
        int wi = __float_as_int(w);
        float w0 = __int_as_float(__builtin_amdgcn_ds_bpermute(a0i, wi));
        float w1 = __int_as_float(__builtin_amdgcn_ds_bpermute(a1i, wi));
        float w2 = __int_as_float(__builtin_amdgcn_ds_bpermute(a2i, wi));
        float w3 = __int_as_float(__builtin_amdgcn_ds_bpermute(a3i, wi));
        den += (w0 + w1) + (w2 + w3);
        accL += x0L * sp2(w0) + x1L * sp2(w1) + x2L * sp2(w2) + x3L * sp2(w3);
        accH += x0H * sp2(w0) + x1H * sp2(w1) + x2H * sp2(w2) + x3H * sp2(w3);
    }
    for (; p < p1; ++p) {
        int pk = packed[p];
        int s = pk & 0xFFFF, f = pk >> 16;
        unsigned int g = *(const unsigned int*)(xl8 + (size_t)s * 256 + c);
        float sc = alpha[s] + ((f == 0) ? ab0 : ((f == 1) ? ab1 : ab2));
        f32x2 xL, xH;
        fp8dec(g, xL, xH);
        f32x2 pL = (f == 0) ? r0L : ((f == 1) ? r1L : r2L);
        f32x2 pH = (f == 0) ? r0H : ((f == 1) ? r1H : r2H);
        float q = wsum64(adot_pk(xL, xH, pL, pH, a4L, a4H)) + sc;
        float w = exp2f(q);
        den += w;
        accL += xL * sp2(w);
        accH += xH * sp2(w);
    }
    float inv = 1.f / den;
    f32x2 bvL = *(const f32x2*)(biasp + c), bvH = *(const f32x2*)(biasp + c + 2);
    f32x2 oL = accL * sp2(inv) + bvL;
    f32x2 oH = accH * sp2(inv) + bvH;
    ((uint2*)(h2b + (size_t)d * 256))[lane] =
        make_uint2(bf16pack(oL.x, oL.y), bf16pack(oH.x, oH.y));
}

// ---------- GAT layer 2: wave/dst, 4 groups x 16 lanes x 2 dims ----------
__global__ __launch_bounds__(256) void k_gat32(const unsigned short* __restrict__ xc2,
        const int* __restrict__ rowptrF, const int* __restrict__ packed,
        const float* __restrict__ eaW, const float* __restrict__ loopW,
        const float* __restrict__ att, const float* __restrict__ bias,
        float* __restrict__ out, int n) {
    int wid = (blockIdx.x * blockDim.x + threadIdx.x) >> 6;
    if (wid >= n) return;
    int d = __builtin_amdgcn_readfirstlane(wid);
    int lane = threadIdx.x & 63;
    int g = lane >> 4, li = lane & 15;
    unsigned int uxl = ((const unsigned int*)(xc2 + (size_t)d * 64))[li];
    unsigned int uxr = ((const unsigned int*)(xc2 + (size_t)d * 64 + 32))[li];
    float xl0 = __uint_as_float(uxl << 16), xl1 = __uint_as_float(uxl & 0xFFFF0000u);
    float xr0 = __uint_as_float(uxr << 16), xr1 = __uint_as_float(uxr & 0xFFFF0000u);
    float2 avv = ((const float2*)att)[li];
    float a60 = 0.6f * L2E * avv.x, a61 = 0.6f * L2E * avv.y;
    float a40 = 0.4f * L2E * avv.x, a41 = 0.4f * L2E * avv.y;
    float2 e0 = ((const float2*)eaW)[li];
    float2 e1 = ((const float2*)(eaW + 32))[li];
    float2 e2 = ((const float2*)(eaW + 64))[li];
    float p00 = e0.x + xr0, p01 = e0.y + xr1;
    float p10 = e1.x + xr0, p11 = e1.y + xr1;
    float p20 = e2.x + xr0, p21 = e2.y + xr1;
    float den, acc0, acc1;
    {
        float2 lwv = ((const float2*)loopW)[li];
        float m0 = xl0 + xr0 + lwv.x, m1 = xl1 + xr1 + lwv.y;
        float q = a60 * m0 + a40 * fabsf(m0);
        q = fmaf(a61, m1, q); q = fmaf(a41, fabsf(m1), q);
        q += __shfl_xor(q, 1, 64); q += __shfl_xor(q, 2, 64);
        q += __shfl_xor(q, 4, 64); q += __shfl_xor(q, 8, 64);
        float wself = exp2f(q);
        den  = (g == 0) ? wself : 0.f;
        acc0 = (g == 0) ? wself * xl0 : 0.f;
        acc1 = (g == 0) ? wself * xl1 : 0.f;
    }
    int pA = rowptrF[d * 3], pB = rowptrF[d * 3 + 3];
    int p = pA + g;
    for (; p + 12 < pB; p += 16) {
        int pkA = packed[p], pkB = packed[p + 4];
        int pkC = packed[p + 8], pkD = packed[p + 12];
        unsigned int ua = ((const unsigned int*)(xc2 + (size_t)(pkA & 0xFFFF) * 64))[li];
        unsigned int ub = ((const unsigned int*)(xc2 + (size_t)(pkB & 0xFFFF) * 64))[li];
        unsigned int uc = ((const unsigned int*)(xc2 + (size_t)(pkC & 0xFFFF) * 64))[li];
        unsigned int ud = ((const unsigned int*)(xc2 + (size_t)(pkD & 0xFFFF) * 64))[li];
        int fA = pkA >> 16, fB = pkB >> 16, fC = pkC >> 16, fD = pkD >> 16;
        float prA0 = (fA == 0) ? p00 : ((fA == 1) ? p10 : p20);
        float prA1 = (fA == 0) ? p01 : ((fA == 1) ? p11 : p21);
        float prB0 = (fB == 0) ? p00 : ((fB == 1) ? p10 : p20);
        float prB1 = (fB == 0) ? p01 : ((fB == 1) ? p11 : p21);
        float prC0 = (fC == 0) ? p00 : ((fC == 1) ? p10 : p20);
        float prC1 = (fC == 0) ? p01 : ((fC == 1) ? p11 : p21);
        float prD0 = (fD == 0) ? p00 : ((fD == 1) ? p10 : p20);
        float prD1 = (fD == 0) ? p01 : ((fD == 1) ? p11 : p21);
        float xa0 = __uint_as_float(ua << 16), xa1 = __uint_as_float(ua & 0xFFFF0000u);
        float xb0 = __uint_as_float(ub << 16), xb1 = __uint_as_float(ub & 0xFFFF0000u);
        float xcc0 = __uint_as_float(uc << 16), xcc1 = __uint_as_float(uc & 0xFFFF0000u);
        float xd0 = __uint_as_float(ud << 16), xd1 = __uint_as_float(ud & 0xFFFF0000u);
        float ma0 = xa0 + prA0, ma1 = xa1 + prA1;
        float mb0 = xb0 + prB0, mb1 = xb1 + prB1;
        float mc0 = xcc0 + prC0, mc1 = xcc1 + prC1;
        float md0 = xd0 + prD0, md1 = xd1 + prD1;
        float qa = a60 * ma0 + a40 * fabsf(ma0);
        qa = fmaf(a61, ma1, qa); qa = fmaf(a41, fabsf(ma1), qa);
        float qb = a60 * mb0 + a40 * fabsf(mb0);
        qb = fmaf(a61, mb1, qb); qb = fmaf(a41, fabsf(mb1), qb);
        float qc = a60 * mc0 + a40 * fabsf(mc0);
        qc = fmaf(a61, mc1, qc); qc = fmaf(a41, fabsf(mc1), qc);
        float qd = a60 * md0 + a40 * fabsf(md0);
        qd = fmaf(a61, md1, qd); qd = fmaf(a41, fabsf(md1), qd);
#pragma unroll
        for (int off = 1; off <= 8; off <<= 1) {
            qa += __shfl_xor(qa, off, 64);
            qb += __shfl_xor(qb, off, 64);
            qc += __shfl_xor(qc, off, 64);
            qd += __shfl_xor(qd, off, 64);
        }
        float wa = exp2f(qa), wb = exp2f(qb);
        float wc = exp2f(qc), wd = exp2f(qd);
        den += (wa + wb) + (wc + wd);
        acc0 += wa * xa0 + wb * xb0 + wc * xcc0 + wd * xd0;
        acc1 += wa * xa1 + wb * xb1 + wc * xcc1 + wd * xd1;
    }
    for (; p + 4 < pB; p += 8) {
        int pkA = packed[p], pkB = packed[p + 4];
        unsigned int ua = ((const unsigned int*)(xc2 + (size_t)(pkA & 0xFFFF) * 64))[li];
        unsigned int ub = ((const unsigned int*)(xc2 + (size_t)(pkB & 0xFFFF) * 64))[li];
        int fA = pkA >> 16, fB = pkB >> 16;
        float prA0 = (fA == 0) ? p00 : ((fA == 1) ? p10 : p20);
        float prA1 = (fA == 0) ? p01 : ((fA == 1) ? p11 : p21);
        float prB0 = (fB == 0) ? p00 : ((fB == 1) ? p10 : p20);
        float prB1 = (fB == 0) ? p01 : ((fB == 1) ? p11 : p21);
        float xa0 = __uint_as_float(ua << 16), xa1 = __uint_as_float(ua & 0xFFFF0000u);
        float xb0 = __uint_as_float(ub << 16), xb1 = __uint_as_float(ub & 0xFFFF0000u);
        float ma0 = xa0 + prA0, ma1 = xa1 + prA1;
        float mb0 = xb0 + prB0, mb1 = xb1 + prB1;
        float qa = a60 * ma0 + a40 * fabsf(ma0);
        qa = fmaf(a61, ma1, qa); qa = fmaf(a41, fabsf(ma1), qa);
        float qb = a60 * mb0 + a40 * fabsf(mb0);
        qb = fmaf(a61, mb1, qb); qb = fmaf(a41, fabsf(mb1), qb);
#pragma unroll
        for (int off = 1; off <= 8; off <<= 1) {
            qa += __shfl_xor(qa, off, 64);
            qb += __shfl_xor(qb, off, 64);
        }
        float wa = exp2f(qa), wb = exp2f(qb);
        den += wa + wb;
        acc0 += wa * xa0 + wb * xb0;
        acc1 += wa * xa1 + wb * xb1;
    }
    for (; p < pB; p += 4) {
        int pk = packed[p];
        unsigned int u = ((const unsigned int*)(xc2 + (size_t)(pk & 0xFFFF) * 64))[li];
        int f = pk >> 16;
        float pre0 = (f == 0) ? p00 : ((f == 1) ? p10 : p20);
        float pre1 = (f == 0) ? p01 : ((f == 1) ? p11 : p21);
        float x0 = __uint_as_float(u << 16), x1 = __uint_as_float(u & 0xFFFF0000u);
        float m0 = x0 + pre0, m1 = x1 + pre1;
        float q = a60 * m0 + a40 * fabsf(m0);
        q = fmaf(a61, m1, q); q = fmaf(a41, fabsf(m1), q);
        q += __shfl_xor(q, 1, 64); q += __shfl_xor(q, 2, 64);
        q += __shfl_xor(q, 4, 64); q += __shfl_xor(q, 8, 64);
        float w = exp2f(q);
        den += w;
        acc0 = fmaf(w, x0, acc0);
        acc1 = fmaf(w, x1, acc1);
    }
    acc0 += __shfl_xor(acc0, 16, 64); acc0 += __shfl_xor(acc0, 32, 64);
    acc1 += __shfl_xor(acc1, 16, 64); acc1 += __shfl_xor(acc1, 32, 64);
    den  += __shfl_xor(den, 16, 64);  den  += __shfl_xor(den, 32, 64);
    if (g == 0) {
        float2 bvv = ((const float2*)bias)[li];
        float inv = 1.f / den;
        float2 o;
        o.x = fmaf(acc0, inv, bvv.x);
        o.y = fmaf(acc1, inv, bvv.y);
        ((float2*)(out + (size_t)d * 32))[li] = o;
    }
}

// ---------- fused mean + policy head (last block finalizes) ----------
__global__ __launch_bounds__(256) void k_tail(const float* __restrict__ out2,
        float* __restrict__ gsum, int* __restrict__ done,
        const float* __restrict__ policy_W, const float* __restrict__ policy_b,
        float* __restrict__ out, int n) {
    __shared__ float sh[256];
    __shared__ int lastFlag;
    int t = threadIdx.x;
    int c = t & 31, g = t >> 5;
    float acc = 0.f;
    for (int nd = blockIdx.x * 8 + g; nd < n; nd += gridDim.x * 8)
        acc += out2[(size_t)nd * 32 + c];
    sh[t] = acc;
    __syncthreads();
    if (t < 32) {
        float s2 = 0.f;
#pragma unroll
        for (int gg = 0; gg < 8; ++gg) s2 += sh[gg * 32 + c];
        atomicAdd(&gsum[c], s2);
    }
    __syncthreads();
    if (t == 0) {
        __threadfence();
        int old = atomicAdd(done, 1);
        lastFlag = (old == (int)gridDim.x - 1) ? 1 : 0;
    }
    __syncthreads();
    if (lastFlag) {
        if (t < 32) sh[t] = atomicAdd(&gsum[t], 0.f);
        __syncthreads();
        if (t < 64) {
            float invN = 1.0f / (float)n;
            float a = policy_b[t];
            for (int cc = 0; cc < 32; ++cc) a += sh[cc] * invN * policy_W[cc * 64 + t];
            float mx = wmax64(a);
            float ex = __expf(a - mx);
            float s = wsum64(ex);
            out[t] = ex / s;
        }
    }
}

extern "C" void kernel_launch(void* const* d_in, const int* in_sizes, int n_in,
                              void* d_out, int out_size, void* d_ws, size_t ws_size,
                              hipStream_t stream) {
    const int* x          = (const int*)d_in[0];
    const int* edge_index = (const int*)d_in[1];
    const int* edge_attr  = (const int*)d_in[2];
    const float* text_emb = (const float*)d_in[3];
    const float* type_emb = (const float*)d_in[4];
    const float* flow_emb = (const float*)d_in[5];
    const float* pos_table= (const float*)d_in[6];
    const float* pos_W    = (const float*)d_in[7];
    const float* pos_b    = (const float*)d_in[8];
    const float* c1_Wl    = (const float*)d_in[9];
    const float* c1_bl    = (const float*)d_in[10];
    const float* c1_Wr    = (const float*)d_in[11];
    const float* c1_br    = (const float*)d_in[12];
    const float* c1_We    = (const float*)d_in[13];
    const float* c1_att   = (const float*)d_in[14];
    const float* c1_bias  = (const float*)d_in[15];
    const float* c2_Wl    = (const float*)d_in[16];
    const float* c2_bl    = (const float*)d_in[17];
    const float* c2_Wr    = (const float*)d_in[18];
    const float* c2_br    = (const float*)d_in[19];
    const float* c2_We    = (const float*)d_in[20];
    const float* c2_att   = (const float*)d_in[21];
    const float* c2_bias  = (const float*)d_in[22];
    const float* policy_W = (const float*)d_in[23];
    const float* policy_b = (const float*)d_in[24];
    float* out = (float*)d_out;

    const int N = in_sizes[0] / 2;   // 50000
    const int E = in_sizes[1] / 2;   // 800000
    const int n3 = 3 * N;

    char* base = (char*)d_ws;
    size_t off = 0;
    auto alloc = [&](size_t bytes) -> void* {
        void* p = base + off;
        off = (off + bytes + 255) & ~(size_t)255;
        return p;
    };
    unsigned char*  xl8  = (unsigned char*)alloc((size_t)N * 256);
    unsigned short* xrp  = (unsigned short*)alloc((size_t)N * 256 * 2);
    unsigned short* h2b  = (unsigned short*)alloc((size_t)N * 256 * 2);
    unsigned short* xc2  = (unsigned short*)alloc((size_t)N * 64 * 2);
    float*          out2 = (float*)alloc((size_t)N * 32 * 4);
    unsigned short* Bt1  = (unsigned short*)alloc((size_t)512 * 128 * 2);
    unsigned short* Bt2  = (unsigned short*)alloc((size_t)64 * 256 * 2);
    // zero-region: cntF (3N) | cnt3 (4) | gsum (32) | done (4) | alpha (N)
    int*            zreg   = (int*)alloc((size_t)(n3 + 40 + N) * 4);
    int*            cntF   = zreg;
    int*            cnt3   = zreg + n3;
    float*          gsum   = (float*)(zreg + n3 + 4);
    int*            done   = zreg + n3 + 36;
    float*          alpha1 = (float*)(zreg + n3 + 40);
    int*            rowptrF= (int*)alloc((size_t)(n3 + 1) * 4);
    int*            packed = (int*)alloc((size_t)E * 4);
    int*            bsum   = (int*)alloc(256 * 4);
    float*          delta1 = (float*)alloc(4 * 4);
    float*          eaW1p  = (float*)alloc(768 * 4);
    float*          loopW1p= (float*)alloc(256 * 4);
    float*          att1p  = (float*)alloc(256 * 4);
    float*          bias1p = (float*)alloc(256 * 4);
    float*          eaW2   = (float*)alloc(96 * 4);
    float*          loopW2 = (float*)alloc(32 * 4);
    float*          poscS  = (float*)alloc(128 * 4);

    hipMemsetAsync(zreg, 0, (size_t)(n3 + 40 + N) * 4, stream);

    const int EB = (E + 255) / 256;
    k_edges_prep<<<EB + 320 + 1, 256, 0, stream>>>(
        edge_index, edge_attr, cntF, cnt3, E, EB,
        pos_table, pos_W, pos_b, flow_emb, c1_We, c2_We, c1_att, c1_bias,
        eaW1p, att1p, bias1p, eaW2, delta1, poscS,
        c1_Wl, c1_Wr, c2_Wl, c2_Wr, Bt1, Bt2);

    int nb = (n3 + 1023) / 1024;
    k_scan_block<<<nb + 1, 256, 0, stream>>>(cntF, rowptrF, bsum, n3, nb,
        cnt3, poscS, flow_emb, c1_We, c2_We, c1_att, loopW1p, loopW2, delta1, E);

    k_scan_add<<<(n3 + 255) / 256, 256, 0, stream>>>(rowptrF, bsum, cntF, n3, nb);

    k_scatter<<<EB, 256, 0, stream>>>(edge_index, edge_attr, cntF, packed, E);

    k_gemm1<<<(N + 63) / 64, 256, 0, stream>>>(x, text_emb, type_emb, Bt1,
                                               c1_bl, c1_br, c1_att, alpha1, xl8, xrp, N);

    k_gat256<<<(N + 3) / 4, 256, 0, stream>>>(xl8, xrp, rowptrF, packed, eaW1p, loopW1p,
                                              att1p, bias1p, alpha1, delta1, h2b, N);

    k_gemm2<<<(N + 31) / 32, 256, 0, stream>>>(h2b, Bt2, c2_bl, c2_br, xc2, N);

    k_gat32<<<(N + 3) / 4, 256, 0, stream>>>(xc2, rowptrF, packed, eaW2, loopW2,
                                             c2_att, c2_bias, out2, N);

    k_tail<<<256, 256, 0, stream>>>(out2, gsum, done, policy_W, policy_b, out, N);
}

// Round 14
// 397.072 us; speedup vs baseline: 1.0121x; 1.0121x over previous
//
#include <hip/hip_runtime.h>

typedef __attribute__((ext_vector_type(8))) short bf16x8;
typedef __attribute__((ext_vector_type(4))) float f32x4;
typedef __attribute__((ext_vector_type(2))) float f32x2;

#define L2E 1.4426950408889634f
#define S6A (0.6f * L2E)

static __device__ __forceinline__ float wsum64(float v) {
#pragma unroll
    for (int off = 32; off >= 1; off >>= 1) v += __shfl_xor(v, off, 64);
    return v;
}
static __device__ __forceinline__ float wmax64(float v) {
#pragma unroll
    for (int off = 32; off >= 1; off >>= 1) v = fmaxf(v, __shfl_xor(v, off, 64));
    return v;
}

static __device__ __forceinline__ unsigned short bf16r(float a) {
    unsigned int u = __float_as_uint(a);
    return (unsigned short)((u + 0x7FFFu + ((u >> 16) & 1u)) >> 16);
}
static __device__ __forceinline__ unsigned int bf16pack(float a, float b) {
    unsigned int ua = __float_as_uint(a);
    ua = (ua + 0x7FFFu + ((ua >> 16) & 1u)) >> 16;
    unsigned int ub = __float_as_uint(b);
    ub = (ub + 0x7FFFu + ((ub >> 16) & 1u)) & 0xFFFF0000u;
    return ua | ub;
}
static __device__ __forceinline__ float rflf(float v) {
    return __int_as_float(__builtin_amdgcn_readfirstlane(__float_as_int(v)));
}
static __device__ __forceinline__ f32x2 sp2(float v) {
    f32x2 r; r.x = v; r.y = v; return r;
}

// ---- fp8 e4m3 (HW cvt if available) ----
#if __has_builtin(__builtin_amdgcn_cvt_pk_f32_fp8) && __has_builtin(__builtin_amdgcn_cvt_pk_fp8_f32)
static __device__ __forceinline__ void fp8dec(unsigned int u, f32x2& lo, f32x2& hi) {
    lo = __builtin_amdgcn_cvt_pk_f32_fp8((int)u, false);
    hi = __builtin_amdgcn_cvt_pk_f32_fp8((int)u, true);
}
static __device__ __forceinline__ unsigned int fp8pack4(float a, float b, float c, float d) {
    int u = 0;
    u = __builtin_amdgcn_cvt_pk_fp8_f32(a, b, u, false);
    u = __builtin_amdgcn_cvt_pk_fp8_f32(c, d, u, true);
    return (unsigned int)u;
}
#else
static __device__ __forceinline__ float fp8_1(unsigned int b) {
    return __uint_as_float(((b & 0x80u) << 24) | ((b & 0x7Fu) << 20)) * 0x1p+120f;
}
static __device__ __forceinline__ void fp8dec(unsigned int u, f32x2& lo, f32x2& hi) {
    lo.x = fp8_1(u & 255u); lo.y = fp8_1((u >> 8) & 255u);
    hi.x = fp8_1((u >> 16) & 255u); hi.y = fp8_1(u >> 24);
}
static __device__ __forceinline__ unsigned int fp8enc1(float v) {
    unsigned int s = (__float_as_uint(v) >> 24) & 0x80u;
    float a = fminf(fabsf(v), 448.f);
    unsigned int b;
    if (a < 0.015625f) {
        b = (unsigned int)__float2int_rn(a * 512.f);
    } else {
        unsigned int ua = __float_as_uint(a);
        ua += 0x000FFFFFu + ((ua >> 20) & 1u);
        unsigned int e = ua >> 23;
        if (e > 135u) b = 0x7Eu;
        else b = ((e - 120u) << 3) | ((ua >> 20) & 7u);
    }
    return s | b;
}
static __device__ __forceinline__ unsigned int fp8pack4(float a, float b, float c, float d) {
    return fp8enc1(a) | (fp8enc1(b) << 8) | (fp8enc1(c) << 16) | (fp8enc1(d) << 24);
}
#endif

// packed abs-dot: sum av4_i * |xs_i + pre_i| over 4 dims (2x f32x2)
static __device__ __forceinline__ float adot_pk(f32x2 xlo, f32x2 xhi, f32x2 plo, f32x2 phi,
                                                f32x2 alo, f32x2 ahi) {
    f32x2 mlo = xlo + plo;
    f32x2 mhi = xhi + phi;
    mlo = __builtin_elementwise_max(mlo, -mlo);
    mhi = __builtin_elementwise_max(mhi, -mhi);
    f32x2 qp = mlo * alo + mhi * ahi;
    return qp.x + qp.y;
}

// permutation: natural col j -> MFMA-native storage slot
static __device__ __forceinline__ int permS(int j) {
    int nb = j >> 7, r = j & 127;
    return nb * 128 + (r & 15) * 8 + (r >> 4);
}
static __device__ __forceinline__ int permK(int s) {
    int nb = s >> 7, r = s & 127;
    return nb * 128 + (r & 7) * 16 + (r >> 3);
}

// ---------- fused: edge histogram + weight conversion + flow tables ----------
__global__ void k_edges_prep(const int* __restrict__ ei, const int* __restrict__ ea,
        int* __restrict__ cntF, int* __restrict__ cnt3, int E, int EB,
        const float* __restrict__ pos_table, const float* __restrict__ pos_W,
        const float* __restrict__ pos_b, const float* __restrict__ flow_emb,
        const float* __restrict__ We1, const float* __restrict__ We2,
        const float* __restrict__ att1, const float* __restrict__ bias1,
        float* __restrict__ eaW1p, float* __restrict__ att1p, float* __restrict__ bias1p,
        float* __restrict__ eaW2, float* __restrict__ delta, float* __restrict__ poscS,
        const float* __restrict__ Wl1, const float* __restrict__ Wr1,
        const float* __restrict__ Wl2, const float* __restrict__ Wr2,
        unsigned short* __restrict__ Bt1, unsigned short* __restrict__ Bt2) {
    __shared__ int sh3[3];
    __shared__ float posc[128];
    __shared__ float red4[768];
    int bid = blockIdx.x, t = threadIdx.x;
    if (bid < EB) {
        if (t < 3) sh3[t] = 0;
        __syncthreads();
        int e = bid * 256 + t;
        if (e < E) {
            int dd = ei[E + e];
            int f = ((const int2*)ea)[e].x;
            f = f < 0 ? 0 : (f > 2 ? 2 : f);
            atomicAdd(&cntF[dd * 3 + f], 1);
            atomicAdd(&sh3[f], 1);
        }
        __syncthreads();
        if (t < 3) atomicAdd(&cnt3[t], sh3[t]);
        return;
    }
    if (bid < EB + 320) {
        int i = (bid - EB) * 256 + t;
        if (i < 512 * 128) {
            int nn = i >> 7, k = i & 127;
            float v = (nn < 256) ? Wl1[(size_t)k * 256 + nn] : Wr1[(size_t)k * 256 + nn - 256];
            Bt1[i] = bf16r(v);
        } else {
            int j = i - 512 * 128;
            if (j < 64 * 256) {
                int nn = j >> 8, s = j & 255;
                int kk = permK(s);
                float v = (nn < 32) ? Wl2[(size_t)kk * 32 + nn] : Wr2[(size_t)kk * 32 + nn - 32];
                Bt2[j] = bf16r(v);
            }
        }
        return;
    }
    // tables block (cnt3-independent)
    if (t < 128) {
        const float* row = pos_table + 5120 * 128;
        float a = pos_b[t];
        for (int k = 0; k < 128; ++k) a += row[k] * pos_W[k * 128 + t];
        posc[t] = a;
        poscS[t] = a;
    }
    __syncthreads();
    {
        int j = t;
        float a0 = 0.f, a1 = 0.f, a2 = 0.f;
        for (int k = 0; k < 128; ++k) {
            float w = We1[k * 256 + j];
            float pc = posc[k];
            a0 += (flow_emb[k] + pc) * w;
            a1 += (flow_emb[128 + k] + pc) * w;
            a2 += (flow_emb[256 + k] + pc) * w;
        }
        int s = permS(j);
        eaW1p[s] = a0; eaW1p[256 + s] = a1; eaW1p[512 + s] = a2;
        att1p[s] = att1[j];
        bias1p[s] = bias1[j];
        float avj = att1[j];
        red4[t] = avj * a0; red4[256 + t] = avj * a1; red4[512 + t] = avj * a2;
    }
    __syncthreads();
    if (t < 3) {
        float s = 0.f;
        const float* rr = red4 + t * 256;
        for (int k = 0; k < 256; ++k) s += rr[k];
        delta[t] = s * S6A;
    }
    if (t < 32) {
        int j = t;
        float a0 = 0.f, a1 = 0.f, a2 = 0.f;
        for (int k = 0; k < 128; ++k) {
            float w = We2[k * 32 + j];
            float pc = posc[k];
            a0 += (flow_emb[k] + pc) * w;
            a1 += (flow_emb[128 + k] + pc) * w;
            a2 += (flow_emb[256 + k] + pc) * w;
        }
        eaW2[j] = a0; eaW2[32 + j] = a1; eaW2[64 + j] = a2;
    }
}

// ---------- scan blocks + loop-attr (cnt3-dependent) tables ----------
__global__ __launch_bounds__(256) void k_scan_block(const int* __restrict__ cnt,
        int* __restrict__ rowptr, int* __restrict__ bsum, int n, int nb,
        const int* __restrict__ cnt3, const float* __restrict__ poscS,
        const float* __restrict__ flow_emb, const float* __restrict__ We1,
        const float* __restrict__ We2, const float* __restrict__ att1,
        float* __restrict__ loopW1p, float* __restrict__ loopW2,
        float* __restrict__ delta, int E) {
    __shared__ int sh[256];
    __shared__ float lv[128];
    __shared__ float red[256];
    int b = blockIdx.x, t = threadIdx.x;
    if (b == nb) {  // loop-attr tables
        if (t < 128) {
            float invE = 1.0f / (float)E;
            lv[t] = ((float)cnt3[0] * flow_emb[t] + (float)cnt3[1] * flow_emb[128 + t] +
                     (float)cnt3[2] * flow_emb[256 + t]) * invE + poscS[t];
        }
        __syncthreads();
        {
            int j = t;
            float al = 0.f;
            for (int k = 0; k < 128; ++k) al += lv[k] * We1[k * 256 + j];
            loopW1p[permS(j)] = al;
            red[t] = att1[j] * al;
        }
        __syncthreads();
        if (t == 0) {
            float s = 0.f;
            for (int k = 0; k < 256; ++k) s += red[k];
            delta[3] = s * S6A;
        }
        if (t < 32) {
            float al = 0.f;
            for (int k = 0; k < 128; ++k) al += lv[k] * We2[k * 32 + t];
            loopW2[t] = al;
        }
        return;
    }
    int base = b * 1024 + t * 4;
    int v0 = base + 0 < n ? cnt[base + 0] : 0;
    int v1 = base + 1 < n ? cnt[base + 1] : 0;
    int v2 = base + 2 < n ? cnt[base + 2] : 0;
    int v3 = base + 3 < n ? cnt[base + 3] : 0;
    int tot = v0 + v1 + v2 + v3;
    sh[t] = tot;
    __syncthreads();
    for (int off = 1; off < 256; off <<= 1) {
        int x = (t >= off) ? sh[t - off] : 0;
        __syncthreads();
        sh[t] += x;
        __syncthreads();
    }
    int excl = (t > 0) ? sh[t - 1] : 0;
    if (base + 0 < n) rowptr[base + 0] = excl;
    if (base + 1 < n) rowptr[base + 1] = excl + v0;
    if (base + 2 < n) rowptr[base + 2] = excl + v0 + v1;
    if (base + 3 < n) rowptr[base + 3] = excl + v0 + v1 + v2;
    if (t == 255) bsum[b] = sh[255];
}

// fused lookback: adds prefix of bsum; block 0 also writes rowptr[n] = total
__global__ __launch_bounds__(256) void k_scan_add(int* __restrict__ rowptr,
        const int* __restrict__ bsum, int* __restrict__ wptr, int n, int nb) {
    __shared__ int red[256];
    int b = blockIdx.x, t = threadIdx.x;
    int lim = b >> 2;
    int local = 0;
    for (int k = t; k < lim; k += 256) local += bsum[k];
    red[t] = local;
    __syncthreads();
    for (int s = 128; s > 0; s >>= 1) {
        if (t < s) red[t] += red[t + s];
        __syncthreads();
    }
    int P = red[0];
    if (b == 0) {
        P = 0;
        int tot = 0;
        for (int k = t; k < nb; k += 256) tot += bsum[k];
        __syncthreads();
        red[t] = tot;
        __syncthreads();
        for (int s = 128; s > 0; s >>= 1) {
            if (t < s) red[t] += red[t + s];
            __syncthreads();
        }
        if (t == 0) rowptr[n] = red[0];
    }
    int i = b * 256 + t;
    if (i < n) {
        int v = rowptr[i] + P;
        rowptr[i] = v;
        wptr[i] = v;
    }
}

// ---------- scatter (standalone, no LDS -> full occupancy) ----------
__global__ void k_scatter(const int* __restrict__ ei, const int* __restrict__ ea,
                          int* __restrict__ wptr, int* __restrict__ packed, int E) {
    int e = blockIdx.x * blockDim.x + threadIdx.x;
    if (e >= E) return;
    int s = ei[e], dd = ei[E + e];
    int f = ((const int2*)ea)[e].x;
    f = f < 0 ? 0 : (f > 2 ? 2 : f);
    int p = atomicAdd(&wptr[dd * 3 + f], 1);
    packed[p] = s | (f << 16);
}

// ---------- GEMM 1 (MFMA) + alpha: xl8[N][256] fp8 perm, xrp[N][256] bf16 perm ----------
__global__ __launch_bounds__(256) void k_gemm1(const int* __restrict__ x,
        const float* __restrict__ text_emb, const float* __restrict__ type_emb,
        const unsigned short* __restrict__ Bt,
        const float* __restrict__ bl, const float* __restrict__ br,
        const float* __restrict__ att, float* __restrict__ alpha,
        unsigned char* __restrict__ xl8, unsigned short* __restrict__ xrp, int n) {
    __shared__ unsigned short Ash[64][136];
    __shared__ unsigned short Bsh[128][136];
    int t = threadIdx.x;
    int node0 = blockIdx.x * 64;
    for (int i = t; i < 64 * 128; i += 256) {
        int r = i >> 7, cc = i & 127;
        int nd = node0 + r;
        float v = 0.f;
        if (nd < n)
            v = (cc < 64) ? text_emb[(size_t)x[nd * 2] * 64 + cc]
                          : type_emb[(size_t)x[nd * 2 + 1] * 64 + (cc - 64)];
        Ash[r][cc] = bf16r(v);
    }
    int wave = t >> 6, lane = t & 63;
    int m = lane & 15, q = lane >> 4;
    for (int nb = 0; nb < 4; ++nb) {
        __syncthreads();
        for (int i = t; i < 128 * 16; i += 256) {
            int r = i >> 4, cs = i & 15;
            uint4 v = ((const uint4*)(Bt + (size_t)(nb * 128 + r) * 128))[cs];
            *(uint4*)&Bsh[r][cs * 8] = v;
        }
        __syncthreads();
        f32x4 acc[8];
#pragma unroll
        for (int nt = 0; nt < 8; ++nt) acc[nt] = (f32x4){0.f, 0.f, 0.f, 0.f};
#pragma unroll
        for (int k = 0; k < 128; k += 32) {
            bf16x8 a = *(const bf16x8*)&Ash[wave * 16 + m][k + q * 8];
#pragma unroll
            for (int nt = 0; nt < 8; ++nt) {
                bf16x8 b = *(const bf16x8*)&Bsh[nt * 16 + m][k + q * 8];
                acc[nt] = __builtin_amdgcn_mfma_f32_16x16x32_bf16(a, b, acc[nt], 0, 0, 0);
            }
        }
        float bv[8];
#pragma unroll
        for (int nt = 0; nt < 8; ++nt) {
            int ng = nb * 128 + nt * 16 + m;
            bv[nt] = (nb < 2) ? bl[ng] : br[ng - 256];
        }
#pragma unroll
        for (int r = 0; r < 4; ++r) {
            int node = node0 + wave * 16 + q * 4 + r;
            if (node >= n) continue;
            if (nb < 2) {
                unsigned int u0 = fp8pack4(acc[0][r] + bv[0], acc[1][r] + bv[1],
                                           acc[2][r] + bv[2], acc[3][r] + bv[3]);
                unsigned int u1 = fp8pack4(acc[4][r] + bv[4], acc[5][r] + bv[5],
                                           acc[6][r] + bv[6], acc[7][r] + bv[7]);
                *(uint2*)(xl8 + (size_t)node * 256 + nb * 128 + m * 8) = make_uint2(u0, u1);
            } else {
                uint4 o;
                o.x = bf16pack(acc[0][r] + bv[0], acc[1][r] + bv[1]);
                o.y = bf16pack(acc[2][r] + bv[2], acc[3][r] + bv[3]);
                o.z = bf16pack(acc[4][r] + bv[4], acc[5][r] + bv[5]);
                o.w = bf16pack(acc[6][r] + bv[6], acc[7][r] + bv[7]);
                *(uint4*)(xrp + (size_t)node * 256 + (nb - 2) * 128 + m * 8) = o;
            }
        }
        if (nb < 2) {
            float p0 = 0.f, p1 = 0.f, p2 = 0.f, p3 = 0.f;
#pragma unroll
            for (int nt = 0; nt < 8; ++nt) {
                int ng = nb * 128 + nt * 16 + m;
                float avv = att[ng];
                p0 = fmaf(avv, acc[nt][0] + bv[nt], p0);
                p1 = fmaf(avv, acc[nt][1] + bv[nt], p1);
                p2 = fmaf(avv, acc[nt][2] + bv[nt], p2);
                p3 = fmaf(avv, acc[nt][3] + bv[nt], p3);
            }
#pragma unroll
            for (int off = 1; off <= 8; off <<= 1) {
                p0 += __shfl_xor(p0, off, 64);
                p1 += __shfl_xor(p1, off, 64);
                p2 += __shfl_xor(p2, off, 64);
                p3 += __shfl_xor(p3, off, 64);
            }
            if (m == 0) {
                int nodeb = node0 + wave * 16 + q * 4;
                if (nodeb + 0 < n) atomicAdd(&alpha[nodeb + 0], p0 * S6A);
                if (nodeb + 1 < n) atomicAdd(&alpha[nodeb + 1], p1 * S6A);
                if (nodeb + 2 < n) atomicAdd(&alpha[nodeb + 2], p2 * S6A);
                if (nodeb + 3 < n) atomicAdd(&alpha[nodeb + 3], p3 * S6A);
            }
        }
    }
}

// ---------- GEMM 2 (MFMA) ----------
__global__ __launch_bounds__(256) void k_gemm2(const unsigned short* __restrict__ h2b,
        const unsigned short* __restrict__ Bt,
        const float* __restrict__ bl, const float* __restrict__ br,
        unsigned short* __restrict__ xc, int n) {
    __shared__ unsigned short Ash[32][264];
    __shared__ unsigned short Bsh[64][264];
    int t = threadIdx.x;
    int node0 = blockIdx.x * 32;
    for (int i = t; i < 32 * 32; i += 256) {
        int r = i >> 5, cs = i & 31;
        int nd = node0 + r;
        uint4 v = make_uint4(0u, 0u, 0u, 0u);
        if (nd < n) v = ((const uint4*)(h2b + (size_t)nd * 256))[cs];
        *(uint4*)&Ash[r][cs * 8] = v;
    }
    for (int i = t; i < 64 * 32; i += 256) {
        int r = i >> 5, cs = i & 31;
        uint4 v = ((const uint4*)(Bt + (size_t)r * 256))[cs];
        *(uint4*)&Bsh[r][cs * 8] = v;
    }
    __syncthreads();
    int wave = t >> 6, lane = t & 63;
    int m = lane & 15, q = lane >> 4;
    int mrow = (wave >> 1) * 16;
    int nh   = (wave & 1) * 32;
    f32x4 acc[2];
    acc[0] = (f32x4){0.f, 0.f, 0.f, 0.f};
    acc[1] = (f32x4){0.f, 0.f, 0.f, 0.f};
#pragma unroll
    for (int k = 0; k < 256; k += 32) {
        bf16x8 a = *(const bf16x8*)&Ash[mrow + m][k + q * 8];
#pragma unroll
        for (int nt = 0; nt < 2; ++nt) {
            bf16x8 b = *(const bf16x8*)&Bsh[nh + nt * 16 + m][k + q * 8];
            acc[nt] = __builtin_amdgcn_mfma_f32_16x16x32_bf16(a, b, acc[nt], 0, 0, 0);
        }
    }
#pragma unroll
    for (int r = 0; r < 4; ++r) {
        int node = node0 + mrow + q * 4 + r;
        if (node < n) {
#pragma unroll
            for (int nt = 0; nt < 2; ++nt) {
                int ng = nh + nt * 16 + m;
                float bvv = (ng < 32) ? bl[ng] : br[ng - 32];
                xc[(size_t)node * 64 + ng] = bf16r(acc[nt][r] + bvv);
            }
        }
    }
}

// ---------- GAT layer 1: wave/dst (128-thread blocks: less wave imbalance) ----------
__global__ __launch_bounds__(128) void k_gat256(const unsigned char* __restrict__ xl8,
        const unsigned short* __restrict__ xrp,
        const int* __restrict__ rowptrF, const int* __restrict__ packed,
        const float* __restrict__ eaWp, const float* __restrict__ loopWp,
        const float* __restrict__ attp, const float* __restrict__ biasp,
        const float* __restrict__ alpha, const float* __restrict__ delta,
        unsigned short* __restrict__ h2b, int n) {
    int wid = (blockIdx.x * blockDim.x + threadIdx.x) >> 6;
    if (wid >= n) return;
    int d = __builtin_amdgcn_readfirstlane(wid);
    int lane = threadIdx.x & 63;
    int c = lane * 4;
    const float S4 = 0.4f * L2E;
    f32x2 xldL, xldH;
    fp8dec(*(const unsigned int*)(xl8 + (size_t)d * 256 + c), xldL, xldH);
    uint2 uxr = ((const uint2*)(xrp + (size_t)d * 256))[lane];
    f32x2 xrdL, xrdH;
    xrdL.x = __uint_as_float(uxr.x << 16); xrdL.y = __uint_as_float(uxr.x & 0xFFFF0000u);
    xrdH.x = __uint_as_float(uxr.y << 16); xrdH.y = __uint_as_float(uxr.y & 0xFFFF0000u);
    f32x2 avL = *(const f32x2*)(attp + c), avH = *(const f32x2*)(attp + c + 2);
    f32x2 a4L = avL * sp2(S4), a4H = avH * sp2(S4);
    f32x2 gp = avL * xrdL + avH * xrdH;
    float gd = rflf(wsum64(gp.x + gp.y) * S6A);
    float ab0 = gd + delta[0], ab1 = gd + delta[1], ab2 = gd + delta[2];
    float ab3 = gd + delta[3];
    float alphad = alpha[d];
    f32x2 r0L = *(const f32x2*)(eaWp + c) + xrdL;
    f32x2 r0H = *(const f32x2*)(eaWp + c + 2) + xrdH;
    f32x2 r1L = *(const f32x2*)(eaWp + 256 + c) + xrdL;
    f32x2 r1H = *(const f32x2*)(eaWp + 256 + c + 2) + xrdH;
    f32x2 r2L = *(const f32x2*)(eaWp + 512 + c) + xrdL;
    f32x2 r2H = *(const f32x2*)(eaWp + 512 + c + 2) + xrdH;
    f32x2 lwL = *(const f32x2*)(loopWp + c) + xrdL;
    f32x2 lwH = *(const f32x2*)(loopWp + c + 2) + xrdH;
    int jj = lane & 15;
    int a0i = jj << 2, a1i = (jj + 16) << 2, a2i = (jj + 32) << 2, a3i = (jj + 48) << 2;
    bool bq0 = (lane & 16) != 0, bq1 = (lane & 32) != 0;
    float den;
    f32x2 accL, accH;
    {
        float q = wsum64(adot_pk(xldL, xldH, lwL, lwH, a4L, a4H)) + alphad + ab3;
        float wself = exp2f(q);
        den = wself;
        accL = xldL * sp2(wself);
        accH = xldH * sp2(wself);
    }
    int p = rowptrF[d * 3], p1 = rowptrF[d * 3 + 3];
    for (; p + 4 <= p1; p += 4) {
        int pk0 = packed[p],     pk1 = packed[p + 1];
        int pk2 = packed[p + 2], pk3 = packed[p + 3];
        int s0 = pk0 & 0xFFFF, s1 = pk1 & 0xFFFF;
        int s2 = pk2 & 0xFFFF, s3 = pk3 & 0xFFFF;
        int f0 = pk0 >> 16, f1 = pk1 >> 16, f2 = pk2 >> 16, f3 = pk3 >> 16;
        unsigned int g0 = *(const unsigned int*)(xl8 + (size_t)s0 * 256 + c);
        unsigned int g1 = *(const unsigned int*)(xl8 + (size_t)s1 * 256 + c);
        unsigned int g2 = *(const unsigned int*)(xl8 + (size_t)s2 * 256 + c);
        unsigned int g3 = *(const unsigned int*)(xl8 + (size_t)s3 * 256 + c);
        float sc0 = alpha[s0] + ((f0 == 0) ? ab0 : ((f0 == 1) ? ab1 : ab2));
        float sc1 = alpha[s1] + ((f1 == 0) ? ab0 : ((f1 == 1) ? ab1 : ab2));
        float sc2 = alpha[s2] + ((f2 == 0) ? ab0 : ((f2 == 1) ? ab1 : ab2));
        float sc3 = alpha[s3] + ((f3 == 0) ? ab0 : ((f3 == 1) ? ab1 : ab2));
        f32x2 x0L, x0H, x1L, x1H, x2L, x2H, x3L, x3H;
        fp8dec(g0, x0L, x0H); fp8dec(g1, x1L, x1H);
        fp8dec(g2, x2L, x2H); fp8dec(g3, x3L, x3H);
        float q0, q1, q2, q3;
        if (f0 == f3) {
            f32x2 pL = (f0 == 0) ? r0L : ((f0 == 1) ? r1L : r2L);
            f32x2 pH = (f0 == 0) ? r0H : ((f0 == 1) ? r1H : r2H);
            q0 = adot_pk(x0L, x0H, pL, pH, a4L, a4H);
            q1 = adot_pk(x1L, x1H, pL, pH, a4L, a4H);
            q2 = adot_pk(x2L, x2H, pL, pH, a4L, a4H);
            q3 = adot_pk(x3L, x3H, pL, pH, a4L, a4H);
        } else {
            f32x2 p0L = (f0 == 0) ? r0L : ((f0 == 1) ? r1L : r2L);
            f32x2 p0H = (f0 == 0) ? r0H : ((f0 == 1) ? r1H : r2H);
            f32x2 p1L_ = (f1 == 0) ? r0L : ((f1 == 1) ? r1L : r2L);
            f32x2 p1H_ = (f1 == 0) ? r0H : ((f1 == 1) ? r1H : r2H);
            f32x2 p2L = (f2 == 0) ? r0L : ((f2 == 1) ? r1L : r2L);
            f32x2 p2H = (f2 == 0) ? r0H : ((f2 == 1) ? r1H : r2H);
            f32x2 p3L = (f3 == 0) ? r0L : ((f3 == 1) ? r1L : r2L);
            f32x2 p3H = (f3 == 0) ? r0H : ((f3 == 1) ? r1H : r2H);
            q0 = adot_pk(x0L, x0H, p0L, p0H, a4L, a4H);
            q1 = adot_pk(x1L, x1H, p1L_, p1H_, a4L, a4H);
            q2 = adot_pk(x2L, x2H, p2L, p2H, a4L, a4H);
            q3 = adot_pk(x3L, x3H, p3L, p3H, a4L, a4H);
        }
        q0 += __shfl_xor(q0, 16, 64); q1 += __shfl_xor(q1, 16, 64);
        q2 += __shfl_xor(q2, 16, 64); q3 += __shfl_xor(q3, 16, 64);
        q0 += __shfl_xor(q0, 32, 64); q1 += __shfl_xor(q1, 32, 64);
        q2 += __shfl_xor(q2, 32, 64); q3 += __shfl_xor(q3, 32, 64);
        float r01 = bq0 ? q1 : q0, r23 = bq0 ? q3 : q2;
        float rr = bq1 ? r23 : r01;
        rr += __shfl_xor(rr, 1, 64); rr += __shfl_xor(rr, 2, 64);
        rr += __shfl_xor(rr, 4, 64); rr += __shfl_xor(rr, 8, 64);
        float s01 = bq0 ? sc1 : sc0, s23 = bq0 ? sc3 : sc2;
        float scv = bq1 ? s23 : s01;
        float w = exp2f(rr + scv);
        int wi = __float_as_int(w);
        float w0 = __int_as_float(__builtin_amdgcn_ds_bpermute(a0i, wi));
        float w1 = __int_as_float(__builtin_amdgcn_ds_bpermute(a1i, wi));
        float w2 = __int_as_float(__builtin_amdgcn_ds_bpermute(a2i, wi));
        float w3 = __int_as_float(__builtin_amdgcn_ds_bpermute(a3i, wi));
        den += (w0 + w1) + (w2 + w3);
        accL += x0L * sp2(w0) + x1L * sp2(w1) + x2L * sp2(w2) + x3L * sp2(w3);
        accH += x0H * sp2(w0) + x1H * sp2(w1) + x2H * sp2(w2) + x3H * sp2(w3);
    }
    for (; p < p1; ++p) {
        int pk = packed[p];
        int s = pk & 0xFFFF, f = pk >> 16;
        unsigned int g = *(const unsigned int*)(xl8 + (size_t)s * 256 + c);
        float sc = alpha[s] + ((f == 0) ? ab0 : ((f == 1) ? ab1 : ab2));
        f32x2 xL, xH;
        fp8dec(g, xL, xH);
        f32x2 pL = (f == 0) ? r0L : ((f == 1) ? r1L : r2L);
        f32x2 pH = (f == 0) ? r0H : ((f == 1) ? r1H : r2H);
        float q = wsum64(adot_pk(xL, xH, pL, pH, a4L, a4H)) + sc;
        float w = exp2f(q);
        den += w;
        accL += xL * sp2(w);
        accH += xH * sp2(w);
    }
    float inv = 1.f / den;
    f32x2 bvL = *(const f32x2*)(biasp + c), bvH = *(const f32x2*)(biasp + c + 2);
    f32x2 oL = accL * sp2(inv) + bvL;
    f32x2 oH = accH * sp2(inv) + bvH;
    ((uint2*)(h2b + (size_t)d * 256))[lane] =
        make_uint2(bf16pack(oL.x, oL.y), bf16pack(oH.x, oH.y));
}

// ---------- GAT layer 2: wave/dst (128-thread blocks), 4 groups x 16 lanes x 2 dims ----------
__global__ __launch_bounds__(128) void k_gat32(const unsigned short* __restrict__ xc2,
        const int* __restrict__ rowptrF, const int* __restrict__ packed,
        const float* __restrict__ eaW, const float* __restrict__ loopW,
        const float* __restrict__ att, const float* __restrict__ bias,
        float* __restrict__ out, int n) {
    int wid = (blockIdx.x * blockDim.x + threadIdx.x) >> 6;
    if (wid >= n) return;
    int d = __builtin_amdgcn_readfirstlane(wid);
    int lane = threadIdx.x & 63;
    int g = lane >> 4, li = lane & 15;
    unsigned int uxl = ((const unsigned int*)(xc2 + (size_t)d * 64))[li];
    unsigned int uxr = ((const unsigned int*)(xc2 + (size_t)d * 64 + 32))[li];
    float xl0 = __uint_as_float(uxl << 16), xl1 = __uint_as_float(uxl & 0xFFFF0000u);
    float xr0 = __uint_as_float(uxr << 16), xr1 = __uint_as_float(uxr & 0xFFFF0000u);
    float2 avv = ((const float2*)att)[li];
    float a60 = 0.6f * L2E * avv.x, a61 = 0.6f * L2E * avv.y;
    float a40 = 0.4f * L2E * avv.x, a41 = 0.4f * L2E * avv.y;
    float2 e0 = ((const float2*)eaW)[li];
    float2 e1 = ((const float2*)(eaW + 32))[li];
    float2 e2 = ((const float2*)(eaW + 64))[li];
    float p00 = e0.x + xr0, p01 = e0.y + xr1;
    float p10 = e1.x + xr0, p11 = e1.y + xr1;
    float p20 = e2.x + xr0, p21 = e2.y + xr1;
    float den, acc0, acc1;
    {
        float2 lwv = ((const float2*)loopW)[li];
        float m0 = xl0 + xr0 + lwv.x, m1 = xl1 + xr1 + lwv.y;
        float q = a60 * m0 + a40 * fabsf(m0);
        q = fmaf(a61, m1, q); q = fmaf(a41, fabsf(m1), q);
        q += __shfl_xor(q, 1, 64); q += __shfl_xor(q, 2, 64);
        q += __shfl_xor(q, 4, 64); q += __shfl_xor(q, 8, 64);
        float wself = exp2f(q);
        den  = (g == 0) ? wself : 0.f;
        acc0 = (g == 0) ? wself * xl0 : 0.f;
        acc1 = (g == 0) ? wself * xl1 : 0.f;
    }
    int pA = rowptrF[d * 3], pB = rowptrF[d * 3 + 3];
    int p = pA + g;
    for (; p + 12 < pB; p += 16) {
        int pkA = packed[p], pkB = packed[p + 4];
        int pkC = packed[p + 8], pkD = packed[p + 12];
        unsigned int ua = ((const unsigned int*)(xc2 + (size_t)(pkA & 0xFFFF) * 64))[li];
        unsigned int ub = ((const unsigned int*)(xc2 + (size_t)(pkB & 0xFFFF) * 64))[li];
        unsigned int uc = ((const unsigned int*)(xc2 + (size_t)(pkC & 0xFFFF) * 64))[li];
        unsigned int ud = ((const unsigned int*)(xc2 + (size_t)(pkD & 0xFFFF) * 64))[li];
        int fA = pkA >> 16, fB = pkB >> 16, fC = pkC >> 16, fD = pkD >> 16;
        float prA0 = (fA == 0) ? p00 : ((fA == 1) ? p10 : p20);
        float prA1 = (fA == 0) ? p01 : ((fA == 1) ? p11 : p21);
        float prB0 = (fB == 0) ? p00 : ((fB == 1) ? p10 : p20);
        float prB1 = (fB == 0) ? p01 : ((fB == 1) ? p11 : p21);
        float prC0 = (fC == 0) ? p00 : ((fC == 1) ? p10 : p20);
        float prC1 = (fC == 0) ? p01 : ((fC == 1) ? p11 : p21);
        float prD0 = (fD == 0) ? p00 : ((fD == 1) ? p10 : p20);
        float prD1 = (fD == 0) ? p01 : ((fD == 1) ? p11 : p21);
        float xa0 = __uint_as_float(ua << 16), xa1 = __uint_as_float(ua & 0xFFFF0000u);
        float xb0 = __uint_as_float(ub << 16), xb1 = __uint_as_float(ub & 0xFFFF0000u);
        float xcc0 = __uint_as_float(uc << 16), xcc1 = __uint_as_float(uc & 0xFFFF0000u);
        float xd0 = __uint_as_float(ud << 16), xd1 = __uint_as_float(ud & 0xFFFF0000u);
        float ma0 = xa0 + prA0, ma1 = xa1 + prA1;
        float mb0 = xb0 + prB0, mb1 = xb1 + prB1;
        float mc0 = xcc0 + prC0, mc1 = xcc1 + prC1;
        float md0 = xd0 + prD0, md1 = xd1 + prD1;
        float qa = a60 * ma0 + a40 * fabsf(ma0);
        qa = fmaf(a61, ma1, qa); qa = fmaf(a41, fabsf(ma1), qa);
        float qb = a60 * mb0 + a40 * fabsf(mb0);
        qb = fmaf(a61, mb1, qb); qb = fmaf(a41, fabsf(mb1), qb);
        float qc = a60 * mc0 + a40 * fabsf(mc0);
        qc = fmaf(a61, mc1, qc); qc = fmaf(a41, fabsf(mc1), qc);
        float qd = a60 * md0 + a40 * fabsf(md0);
        qd = fmaf(a61, md1, qd); qd = fmaf(a41, fabsf(md1), qd);
#pragma unroll
        for (int off = 1; off <= 8; off <<= 1) {
            qa += __shfl_xor(qa, off, 64);
            qb += __shfl_xor(qb, off, 64);
            qc += __shfl_xor(qc, off, 64);
            qd += __shfl_xor(qd, off, 64);
        }
        float wa = exp2f(qa), wb = exp2f(qb);
        float wc = exp2f(qc), wd = exp2f(qd);
        den += (wa + wb) + (wc + wd);
        acc0 += wa * xa0 + wb * xb0 + wc * xcc0 + wd * xd0;
        acc1 += wa * xa1 + wb * xb1 + wc * xcc1 + wd * xd1;
    }
    for (; p + 4 < pB; p += 8) {
        int pkA = packed[p], pkB = packed[p + 4];
        unsigned int ua = ((const unsigned int*)(xc2 + (size_t)(pkA & 0xFFFF) * 64))[li];
        unsigned int ub = ((const unsigned int*)(xc2 + (size_t)(pkB & 0xFFFF) * 64))[li];
        int fA = pkA >> 16, fB = pkB >> 16;
        float prA0 = (fA == 0) ? p00 : ((fA == 1) ? p10 : p20);
        float prA1 = (fA == 0) ? p01 : ((fA == 1) ? p11 : p21);
        float prB0 = (fB == 0) ? p00 : ((fB == 1) ? p10 : p20);
        float prB1 = (fB == 0) ? p01 : ((fB == 1) ? p11 : p21);
        float xa0 = __uint_as_float(ua << 16), xa1 = __uint_as_float(ua & 0xFFFF0000u);
        float xb0 = __uint_as_float(ub << 16), xb1 = __uint_as_float(ub & 0xFFFF0000u);
        float ma0 = xa0 + prA0, ma1 = xa1 + prA1;
        float mb0 = xb0 + prB0, mb1 = xb1 + prB1;
        float qa = a60 * ma0 + a40 * fabsf(ma0);
        qa = fmaf(a61, ma1, qa); qa = fmaf(a41, fabsf(ma1), qa);
        float qb = a60 * mb0 + a40 * fabsf(mb0);
        qb = fmaf(a61, mb1, qb); qb = fmaf(a41, fabsf(mb1), qb);
#pragma unroll
        for (int off = 1; off <= 8; off <<= 1) {
            qa += __shfl_xor(qa, off, 64);
            qb += __shfl_xor(qb, off, 64);
        }
        float wa = exp2f(qa), wb = exp2f(qb);
        den += wa + wb;
        acc0 += wa * xa0 + wb * xb0;
        acc1 += wa * xa1 + wb * xb1;
    }
    for (; p < pB; p += 4) {
        int pk = packed[p];
        unsigned int u = ((const unsigned int*)(xc2 + (size_t)(pk & 0xFFFF) * 64))[li];
        int f = pk >> 16;
        float pre0 = (f == 0) ? p00 : ((f == 1) ? p10 : p20);
        float pre1 = (f == 0) ? p01 : ((f == 1) ? p11 : p21);
        float x0 = __uint_as_float(u << 16), x1 = __uint_as_float(u & 0xFFFF0000u);
        float m0 = x0 + pre0, m1 = x1 + pre1;
        float q = a60 * m0 + a40 * fabsf(m0);
        q = fmaf(a61, m1, q); q = fmaf(a41, fabsf(m1), q);
        q += __shfl_xor(q, 1, 64); q += __shfl_xor(q, 2, 64);
        q += __shfl_xor(q, 4, 64); q += __shfl_xor(q, 8, 64);
        float w = exp2f(q);
        den += w;
        acc0 = fmaf(w, x0, acc0);
        acc1 = fmaf(w, x1, acc1);
    }
    acc0 += __shfl_xor(acc0, 16, 64); acc0 += __shfl_xor(acc0, 32, 64);
    acc1 += __shfl_xor(acc1, 16, 64); acc1 += __shfl_xor(acc1, 32, 64);
    den  += __shfl_xor(den, 16, 64);  den  += __shfl_xor(den, 32, 64);
    if (g == 0) {
        float2 bvv = ((const float2*)bias)[li];
        float inv = 1.f / den;
        float2 o;
        o.x = fmaf(acc0, inv, bvv.x);
        o.y = fmaf(acc1, inv, bvv.y);
        ((float2*)(out + (size_t)d * 32))[li] = o;
    }
}

// ---------- fused mean + policy head (last block finalizes) ----------
__global__ __launch_bounds__(256) void k_tail(const float* __restrict__ out2,
        float* __restrict__ gsum, int* __restrict__ done,
        const float* __restrict__ policy_W, const float* __restrict__ policy_b,
        float* __restrict__ out, int n) {
    __shared__ float sh[256];
    __shared__ int lastFlag;
    int t = threadIdx.x;
    int c = t & 31, g = t >> 5;
    float acc = 0.f;
    for (int nd = blockIdx.x * 8 + g; nd < n; nd += gridDim.x * 8)
        acc += out2[(size_t)nd * 32 + c];
    sh[t] = acc;
    __syncthreads();
    if (t < 32) {
        float s2 = 0.f;
#pragma unroll
        for (int gg = 0; gg < 8; ++gg) s2 += sh[gg * 32 + c];
        atomicAdd(&gsum[c], s2);
    }
    __syncthreads();
    if (t == 0) {
        __threadfence();
        int old = atomicAdd(done, 1);
        lastFlag = (old == (int)gridDim.x - 1) ? 1 : 0;
    }
    __syncthreads();
    if (lastFlag) {
        if (t < 32) sh[t] = atomicAdd(&gsum[t], 0.f);
        __syncthreads();
        if (t < 64) {
            float invN = 1.0f / (float)n;
            float a = policy_b[t];
            for (int cc = 0; cc < 32; ++cc) a += sh[cc] * invN * policy_W[cc * 64 + t];
            float mx = wmax64(a);
            float ex = __expf(a - mx);
            float s = wsum64(ex);
            out[t] = ex / s;
        }
    }
}

extern "C" void kernel_launch(void* const* d_in, const int* in_sizes, int n_in,
                              void* d_out, int out_size, void* d_ws, size_t ws_size,
                              hipStream_t stream) {
    const int* x          = (const int*)d_in[0];
    const int* edge_index = (const int*)d_in[1];
    const int* edge_attr  = (const int*)d_in[2];
    const float* text_emb = (const float*)d_in[3];
    const float* type_emb = (const float*)d_in[4];
    const float* flow_emb = (const float*)d_in[5];
    const float* pos_table= (const float*)d_in[6];
    const float* pos_W    = (const float*)d_in[7];
    const float* pos_b    = (const float*)d_in[8];
    const float* c1_Wl    = (const float*)d_in[9];
    const float* c1_bl    = (const float*)d_in[10];
    const float* c1_Wr    = (const float*)d_in[11];
    const float* c1_br    = (const float*)d_in[12];
    const float* c1_We    = (const float*)d_in[13];
    const float* c1_att   = (const float*)d_in[14];
    const float* c1_bias  = (const float*)d_in[15];
    const float* c2_Wl    = (const float*)d_in[16];
    const float* c2_bl    = (const float*)d_in[17];
    const float* c2_Wr    = (const float*)d_in[18];
    const float* c2_br    = (const float*)d_in[19];
    const float* c2_We    = (const float*)d_in[20];
    const float* c2_att   = (const float*)d_in[21];
    const float* c2_bias  = (const float*)d_in[22];
    const float* policy_W = (const float*)d_in[23];
    const float* policy_b = (const float*)d_in[24];
    float* out = (float*)d_out;

    const int N = in_sizes[0] / 2;   // 50000
    const int E = in_sizes[1] / 2;   // 800000
    const int n3 = 3 * N;

    char* base = (char*)d_ws;
    size_t off = 0;
    auto alloc = [&](size_t bytes) -> void* {
        void* p = base + off;
        off = (off + bytes + 255) & ~(size_t)255;
        return p;
    };
    unsigned char*  xl8  = (unsigned char*)alloc((size_t)N * 256);
    unsigned short* xrp  = (unsigned short*)alloc((size_t)N * 256 * 2);
    unsigned short* h2b  = (unsigned short*)alloc((size_t)N * 256 * 2);
    unsigned short* xc2  = (unsigned short*)alloc((size_t)N * 64 * 2);
    float*          out2 = (float*)alloc((size_t)N * 32 * 4);
    unsigned short* Bt1  = (unsigned short*)alloc((size_t)512 * 128 * 2);
    unsigned short* Bt2  = (unsigned short*)alloc((size_t)64 * 256 * 2);
    // zero-region: cntF (3N) | cnt3 (4) | gsum (32) | done (4) | alpha (N)
    int*            zreg   = (int*)alloc((size_t)(n3 + 40 + N) * 4);
    int*            cntF   = zreg;
    int*            cnt3   = zreg + n3;
    float*          gsum   = (float*)(zreg + n3 + 4);
    int*            done   = zreg + n3 + 36;
    float*          alpha1 = (float*)(zreg + n3 + 40);
    int*            rowptrF= (int*)alloc((size_t)(n3 + 1) * 4);
    int*            packed = (int*)alloc((size_t)E * 4);
    int*            bsum   = (int*)alloc(256 * 4);
    float*          delta1 = (float*)alloc(4 * 4);
    float*          eaW1p  = (float*)alloc(768 * 4);
    float*          loopW1p= (float*)alloc(256 * 4);
    float*          att1p  = (float*)alloc(256 * 4);
    float*          bias1p = (float*)alloc(256 * 4);
    float*          eaW2   = (float*)alloc(96 * 4);
    float*          loopW2 = (float*)alloc(32 * 4);
    float*          poscS  = (float*)alloc(128 * 4);

    hipMemsetAsync(zreg, 0, (size_t)(n3 + 40 + N) * 4, stream);

    const int EB = (E + 255) / 256;
    k_edges_prep<<<EB + 320 + 1, 256, 0, stream>>>(
        edge_index, edge_attr, cntF, cnt3, E, EB,
        pos_table, pos_W, pos_b, flow_emb, c1_We, c2_We, c1_att, c1_bias,
        eaW1p, att1p, bias1p, eaW2, delta1, poscS,
        c1_Wl, c1_Wr, c2_Wl, c2_Wr, Bt1, Bt2);

    int nb = (n3 + 1023) / 1024;
    k_scan_block<<<nb + 1, 256, 0, stream>>>(cntF, rowptrF, bsum, n3, nb,
        cnt3, poscS, flow_emb, c1_We, c2_We, c1_att, loopW1p, loopW2, delta1, E);

    k_scan_add<<<(n3 + 255) / 256, 256, 0, stream>>>(rowptrF, bsum, cntF, n3, nb);

    k_scatter<<<EB, 256, 0, stream>>>(edge_index, edge_attr, cntF, packed, E);

    k_gemm1<<<(N + 63) / 64, 256, 0, stream>>>(x, text_emb, type_emb, Bt1,
                                               c1_bl, c1_br, c1_att, alpha1, xl8, xrp, N);

    k_gat256<<<(N + 1) / 2, 128, 0, stream>>>(xl8, xrp, rowptrF, packed, eaW1p, loopW1p,
                                              att1p, bias1p, alpha1, delta1, h2b, N);

    k_gemm2<<<(N + 31) / 32, 256, 0, stream>>>(h2b, Bt2, c2_bl, c2_br, xc2, N);

    k_gat32<<<(N + 1) / 2, 128, 0, stream>>>(xc2, rowptrF, packed, eaW2, loopW2,
                                             c2_att, c2_bias, out2, N);

    k_tail<<<256, 256, 0, stream>>>(out2, gsum, done, policy_W, policy_b, out, N);
}

// Round 15
// 386.684 us; speedup vs baseline: 1.0393x; 1.0269x over previous
//
#include <hip/hip_runtime.h>

typedef __attribute__((ext_vector_type(8))) short bf16x8;
typedef __attribute__((ext_vector_type(4))) float f32x4;
typedef __attribute__((ext_vector_type(2))) float f32x2;

#define L2E 1.4426950408889634f
#define S6A (0.6f * L2E)

static __device__ __forceinline__ float wsum64(float v) {
#pragma unroll
    for (int off = 32; off >= 1; off >>= 1) v += __shfl_xor(v, off, 64);
    return v;
}
static __device__ __forceinline__ float wmax64(float v) {
#pragma unroll
    for (int off = 32; off >= 1; off >>= 1) v = fmaxf(v, __shfl_xor(v, off, 64));
    return v;
}

static __device__ __forceinline__ unsigned short bf16r(float a) {
    unsigned int u = __float_as_uint(a);
    return (unsigned short)((u + 0x7FFFu + ((u >> 16) & 1u)) >> 16);
}
static __device__ __forceinline__ unsigned int bf16pack(float a, float b) {
    unsigned int ua = __float_as_uint(a);
    ua = (ua + 0x7FFFu + ((ua >> 16) & 1u)) >> 16;
    unsigned int ub = __float_as_uint(b);
    ub = (ub + 0x7FFFu + ((ub >> 16) & 1u)) & 0xFFFF0000u;
    return ua | ub;
}
static __device__ __forceinline__ float rflf(float v) {
    return __int_as_float(__builtin_amdgcn_readfirstlane(__float_as_int(v)));
}
static __device__ __forceinline__ f32x2 sp2(float v) {
    f32x2 r; r.x = v; r.y = v; return r;
}

// ---- fp8 e4m3 (HW cvt if available) ----
#if __has_builtin(__builtin_amdgcn_cvt_pk_f32_fp8) && __has_builtin(__builtin_amdgcn_cvt_pk_fp8_f32)
static __device__ __forceinline__ void fp8dec(unsigned int u, f32x2& lo, f32x2& hi) {
    lo = __builtin_amdgcn_cvt_pk_f32_fp8((int)u, false);
    hi = __builtin_amdgcn_cvt_pk_f32_fp8((int)u, true);
}
static __device__ __forceinline__ unsigned int fp8pack4(float a, float b, float c, float d) {
    int u = 0;
    u = __builtin_amdgcn_cvt_pk_fp8_f32(a, b, u, false);
    u = __builtin_amdgcn_cvt_pk_fp8_f32(c, d, u, true);
    return (unsigned int)u;
}
#else
static __device__ __forceinline__ float fp8_1(unsigned int b) {
    return __uint_as_float(((b & 0x80u) << 24) | ((b & 0x7Fu) << 20)) * 0x1p+120f;
}
static __device__ __forceinline__ void fp8dec(unsigned int u, f32x2& lo, f32x2& hi) {
    lo.x = fp8_1(u & 255u); lo.y = fp8_1((u >> 8) & 255u);
    hi.x = fp8_1((u >> 16) & 255u); hi.y = fp8_1(u >> 24);
}
static __device__ __forceinline__ unsigned int fp8enc1(float v) {
    unsigned int s = (__float_as_uint(v) >> 24) & 0x80u;
    float a = fminf(fabsf(v), 448.f);
    unsigned int b;
    if (a < 0.015625f) {
        b = (unsigned int)__float2int_rn(a * 512.f);
    } else {
        unsigned int ua = __float_as_uint(a);
        ua += 0x000FFFFFu + ((ua >> 20) & 1u);
        unsigned int e = ua >> 23;
        if (e > 135u) b = 0x7Eu;
        else b = ((e - 120u) << 3) | ((ua >> 20) & 7u);
    }
    return s | b;
}
static __device__ __forceinline__ unsigned int fp8pack4(float a, float b, float c, float d) {
    return fp8enc1(a) | (fp8enc1(b) << 8) | (fp8enc1(c) << 16) | (fp8enc1(d) << 24);
}
#endif

// packed abs-dot: sum av4_i * |xs_i + pre_i| over 4 dims (2x f32x2)
static __device__ __forceinline__ float adot_pk(f32x2 xlo, f32x2 xhi, f32x2 plo, f32x2 phi,
                                                f32x2 alo, f32x2 ahi) {
    f32x2 mlo = xlo + plo;
    f32x2 mhi = xhi + phi;
    mlo = __builtin_elementwise_max(mlo, -mlo);
    mhi = __builtin_elementwise_max(mhi, -mhi);
    f32x2 qp = mlo * alo + mhi * ahi;
    return qp.x + qp.y;
}

// permutation: natural col j -> MFMA-native storage slot
static __device__ __forceinline__ int permS(int j) {
    int nb = j >> 7, r = j & 127;
    return nb * 128 + (r & 15) * 8 + (r >> 4);
}
static __device__ __forceinline__ int permK(int s) {
    int nb = s >> 7, r = s & 127;
    return nb * 128 + (r & 7) * 16 + (r >> 3);
}

// ---------- fused: edge histogram + weight conversion + flow tables ----------
__global__ void k_edges_prep(const int* __restrict__ ei, const int* __restrict__ ea,
        int* __restrict__ cntF, int* __restrict__ cnt3, int E, int EB,
        const float* __restrict__ pos_table, const float* __restrict__ pos_W,
        const float* __restrict__ pos_b, const float* __restrict__ flow_emb,
        const float* __restrict__ We1, const float* __restrict__ We2,
        const float* __restrict__ att1, const float* __restrict__ bias1,
        float* __restrict__ eaW1p, float* __restrict__ att1p, float* __restrict__ bias1p,
        float* __restrict__ eaW2, float* __restrict__ delta, float* __restrict__ poscS,
        const float* __restrict__ Wl1, const float* __restrict__ Wr1,
        const float* __restrict__ Wl2, const float* __restrict__ Wr2,
        unsigned short* __restrict__ Bt1, unsigned short* __restrict__ Bt2) {
    __shared__ int sh3[3];
    __shared__ float posc[128];
    __shared__ float red4[768];
    int bid = blockIdx.x, t = threadIdx.x;
    if (bid < EB) {
        if (t < 3) sh3[t] = 0;
        __syncthreads();
        int e = bid * 256 + t;
        if (e < E) {
            int dd = ei[E + e];
            int f = ((const int2*)ea)[e].x;
            f = f < 0 ? 0 : (f > 2 ? 2 : f);
            atomicAdd(&cntF[dd * 3 + f], 1);
            atomicAdd(&sh3[f], 1);
        }
        __syncthreads();
        if (t < 3) atomicAdd(&cnt3[t], sh3[t]);
        return;
    }
    if (bid < EB + 320) {
        int i = (bid - EB) * 256 + t;
        if (i < 512 * 128) {
            int nn = i >> 7, k = i & 127;
            float v = (nn < 256) ? Wl1[(size_t)k * 256 + nn] : Wr1[(size_t)k * 256 + nn - 256];
            Bt1[i] = bf16r(v);
        } else {
            int j = i - 512 * 128;
            if (j < 64 * 256) {
                int nn = j >> 8, s = j & 255;
                int kk = permK(s);
                float v = (nn < 32) ? Wl2[(size_t)kk * 32 + nn] : Wr2[(size_t)kk * 32 + nn - 32];
                Bt2[j] = bf16r(v);
            }
        }
        return;
    }
    // tables block (cnt3-independent)
    if (t < 128) {
        const float* row = pos_table + 5120 * 128;
        float a = pos_b[t];
        for (int k = 0; k < 128; ++k) a += row[k] * pos_W[k * 128 + t];
        posc[t] = a;
        poscS[t] = a;
    }
    __syncthreads();
    {
        int j = t;
        float a0 = 0.f, a1 = 0.f, a2 = 0.f;
        for (int k = 0; k < 128; ++k) {
            float w = We1[k * 256 + j];
            float pc = posc[k];
            a0 += (flow_emb[k] + pc) * w;
            a1 += (flow_emb[128 + k] + pc) * w;
            a2 += (flow_emb[256 + k] + pc) * w;
        }
        int s = permS(j);
        eaW1p[s] = a0; eaW1p[256 + s] = a1; eaW1p[512 + s] = a2;
        att1p[s] = att1[j];
        bias1p[s] = bias1[j];
        float avj = att1[j];
        red4[t] = avj * a0; red4[256 + t] = avj * a1; red4[512 + t] = avj * a2;
    }
    __syncthreads();
    if (t < 3) {
        float s = 0.f;
        const float* rr = red4 + t * 256;
        for (int k = 0; k < 256; ++k) s += rr[k];
        delta[t] = s * S6A;
    }
    if (t < 32) {
        int j = t;
        float a0 = 0.f, a1 = 0.f, a2 = 0.f;
        for (int k = 0; k < 128; ++k) {
            float w = We2[k * 32 + j];
            float pc = posc[k];
            a0 += (flow_emb[k] + pc) * w;
            a1 += (flow_emb[128 + k] + pc) * w;
            a2 += (flow_emb[256 + k] + pc) * w;
        }
        eaW2[j] = a0; eaW2[32 + j] = a1; eaW2[64 + j] = a2;
    }
}

// ---------- scan blocks + loop-attr (cnt3-dependent) tables ----------
__global__ __launch_bounds__(256) void k_scan_block(const int* __restrict__ cnt,
        int* __restrict__ rowptr, int* __restrict__ bsum, int n, int nb,
        const int* __restrict__ cnt3, const float* __restrict__ poscS,
        const float* __restrict__ flow_emb, const float* __restrict__ We1,
        const float* __restrict__ We2, const float* __restrict__ att1,
        float* __restrict__ loopW1p, float* __restrict__ loopW2,
        float* __restrict__ delta, int E) {
    __shared__ int sh[256];
    __shared__ float lv[128];
    __shared__ float red[256];
    int b = blockIdx.x, t = threadIdx.x;
    if (b == nb) {  // loop-attr tables
        if (t < 128) {
            float invE = 1.0f / (float)E;
            lv[t] = ((float)cnt3[0] * flow_emb[t] + (float)cnt3[1] * flow_emb[128 + t] +
                     (float)cnt3[2] * flow_emb[256 + t]) * invE + poscS[t];
        }
        __syncthreads();
        {
            int j = t;
            float al = 0.f;
            for (int k = 0; k < 128; ++k) al += lv[k] * We1[k * 256 + j];
            loopW1p[permS(j)] = al;
            red[t] = att1[j] * al;
        }
        __syncthreads();
        if (t == 0) {
            float s = 0.f;
            for (int k = 0; k < 256; ++k) s += red[k];
            delta[3] = s * S6A;
        }
        if (t < 32) {
            float al = 0.f;
            for (int k = 0; k < 128; ++k) al += lv[k] * We2[k * 32 + t];
            loopW2[t] = al;
        }
        return;
    }
    int base = b * 1024 + t * 4;
    int v0 = base + 0 < n ? cnt[base + 0] : 0;
    int v1 = base + 1 < n ? cnt[base + 1] : 0;
    int v2 = base + 2 < n ? cnt[base + 2] : 0;
    int v3 = base + 3 < n ? cnt[base + 3] : 0;
    int tot = v0 + v1 + v2 + v3;
    sh[t] = tot;
    __syncthreads();
    for (int off = 1; off < 256; off <<= 1) {
        int x = (t >= off) ? sh[t - off] : 0;
        __syncthreads();
        sh[t] += x;
        __syncthreads();
    }
    int excl = (t > 0) ? sh[t - 1] : 0;
    if (base + 0 < n) rowptr[base + 0] = excl;
    if (base + 1 < n) rowptr[base + 1] = excl + v0;
    if (base + 2 < n) rowptr[base + 2] = excl + v0 + v1;
    if (base + 3 < n) rowptr[base + 3] = excl + v0 + v1 + v2;
    if (t == 255) bsum[b] = sh[255];
}

// fused lookback: adds prefix of bsum; block 0 also writes rowptr[n] = total
__global__ __launch_bounds__(256) void k_scan_add(int* __restrict__ rowptr,
        const int* __restrict__ bsum, int* __restrict__ wptr, int n, int nb) {
    __shared__ int red[256];
    int b = blockIdx.x, t = threadIdx.x;
    int lim = b >> 2;
    int local = 0;
    for (int k = t; k < lim; k += 256) local += bsum[k];
    red[t] = local;
    __syncthreads();
    for (int s = 128; s > 0; s >>= 1) {
        if (t < s) red[t] += red[t + s];
        __syncthreads();
    }
    int P = red[0];
    if (b == 0) {
        P = 0;
        int tot = 0;
        for (int k = t; k < nb; k += 256) tot += bsum[k];
        __syncthreads();
        red[t] = tot;
        __syncthreads();
        for (int s = 128; s > 0; s >>= 1) {
            if (t < s) red[t] += red[t + s];
            __syncthreads();
        }
        if (t == 0) rowptr[n] = red[0];
    }
    int i = b * 256 + t;
    if (i < n) {
        int v = rowptr[i] + P;
        rowptr[i] = v;
        wptr[i] = v;
    }
}

// ---------- scatter (standalone, no LDS -> full occupancy) ----------
__global__ void k_scatter(const int* __restrict__ ei, const int* __restrict__ ea,
                          int* __restrict__ wptr, int* __restrict__ packed, int E) {
    int e = blockIdx.x * blockDim.x + threadIdx.x;
    if (e >= E) return;
    int s = ei[e], dd = ei[E + e];
    int f = ((const int2*)ea)[e].x;
    f = f < 0 ? 0 : (f > 2 ? 2 : f);
    int p = atomicAdd(&wptr[dd * 3 + f], 1);
    packed[p] = s | (f << 16);
}

// ---------- GEMM 1 (MFMA) + alpha: xl8[N][256] fp8 perm, xrp[N][256] bf16 perm ----------
__global__ __launch_bounds__(256) void k_gemm1(const int* __restrict__ x,
        const float* __restrict__ text_emb, const float* __restrict__ type_emb,
        const unsigned short* __restrict__ Bt,
        const float* __restrict__ bl, const float* __restrict__ br,
        const float* __restrict__ att, float* __restrict__ alpha,
        unsigned char* __restrict__ xl8, unsigned short* __restrict__ xrp, int n) {
    __shared__ unsigned short Ash[64][136];
    __shared__ unsigned short Bsh[128][136];
    int t = threadIdx.x;
    int node0 = blockIdx.x * 64;
    for (int i = t; i < 64 * 128; i += 256) {
        int r = i >> 7, cc = i & 127;
        int nd = node0 + r;
        float v = 0.f;
        if (nd < n)
            v = (cc < 64) ? text_emb[(size_t)x[nd * 2] * 64 + cc]
                          : type_emb[(size_t)x[nd * 2 + 1] * 64 + (cc - 64)];
        Ash[r][cc] = bf16r(v);
    }
    int wave = t >> 6, lane = t & 63;
    int m = lane & 15, q = lane >> 4;
    for (int nb = 0; nb < 4; ++nb) {
        __syncthreads();
        for (int i = t; i < 128 * 16; i += 256) {
            int r = i >> 4, cs = i & 15;
            uint4 v = ((const uint4*)(Bt + (size_t)(nb * 128 + r) * 128))[cs];
            *(uint4*)&Bsh[r][cs * 8] = v;
        }
        __syncthreads();
        f32x4 acc[8];
#pragma unroll
        for (int nt = 0; nt < 8; ++nt) acc[nt] = (f32x4){0.f, 0.f, 0.f, 0.f};
#pragma unroll
        for (int k = 0; k < 128; k += 32) {
            bf16x8 a = *(const bf16x8*)&Ash[wave * 16 + m][k + q * 8];
#pragma unroll
            for (int nt = 0; nt < 8; ++nt) {
                bf16x8 b = *(const bf16x8*)&Bsh[nt * 16 + m][k + q * 8];
                acc[nt] = __builtin_amdgcn_mfma_f32_16x16x32_bf16(a, b, acc[nt], 0, 0, 0);
            }
        }
        float bv[8];
#pragma unroll
        for (int nt = 0; nt < 8; ++nt) {
            int ng = nb * 128 + nt * 16 + m;
            bv[nt] = (nb < 2) ? bl[ng] : br[ng - 256];
        }
#pragma unroll
        for (int r = 0; r < 4; ++r) {
            int node = node0 + wave * 16 + q * 4 + r;
            if (node >= n) continue;
            if (nb < 2) {
                unsigned int u0 = fp8pack4(acc[0][r] + bv[0], acc[1][r] + bv[1],
                                           acc[2][r] + bv[2], acc[3][r] + bv[3]);
                unsigned int u1 = fp8pack4(acc[4][r] + bv[4], acc[5][r] + bv[5],
                                           acc[6][r] + bv[6], acc[7][r] + bv[7]);
                *(uint2*)(xl8 + (size_t)node * 256 + nb * 128 + m * 8) = make_uint2(u0, u1);
            } else {
                uint4 o;
                o.x = bf16pack(acc[0][r] + bv[0], acc[1][r] + bv[1]);
                o.y = bf16pack(acc[2][r] + bv[2], acc[3][r] + bv[3]);
                o.z = bf16pack(acc[4][r] + bv[4], acc[5][r] + bv[5]);
                o.w = bf16pack(acc[6][r] + bv[6], acc[7][r] + bv[7]);
                *(uint4*)(xrp + (size_t)node * 256 + (nb - 2) * 128 + m * 8) = o;
            }
        }
        if (nb < 2) {
            float p0 = 0.f, p1 = 0.f, p2 = 0.f, p3 = 0.f;
#pragma unroll
            for (int nt = 0; nt < 8; ++nt) {
                int ng = nb * 128 + nt * 16 + m;
                float avv = att[ng];
                p0 = fmaf(avv, acc[nt][0] + bv[nt], p0);
                p1 = fmaf(avv, acc[nt][1] + bv[nt], p1);
                p2 = fmaf(avv, acc[nt][2] + bv[nt], p2);
                p3 = fmaf(avv, acc[nt][3] + bv[nt], p3);
            }
#pragma unroll
            for (int off = 1; off <= 8; off <<= 1) {
                p0 += __shfl_xor(p0, off, 64);
                p1 += __shfl_xor(p1, off, 64);
                p2 += __shfl_xor(p2, off, 64);
                p3 += __shfl_xor(p3, off, 64);
            }
            if (m == 0) {
                int nodeb = node0 + wave * 16 + q * 4;
                if (nodeb + 0 < n) atomicAdd(&alpha[nodeb + 0], p0 * S6A);
                if (nodeb + 1 < n) atomicAdd(&alpha[nodeb + 1], p1 * S6A);
                if (nodeb + 2 < n) atomicAdd(&alpha[nodeb + 2], p2 * S6A);
                if (nodeb + 3 < n) atomicAdd(&alpha[nodeb + 3], p3 * S6A);
            }
        }
    }
}

// ---------- GEMM 2 (MFMA) ----------
__global__ __launch_bounds__(256) void k_gemm2(const unsigned short* __restrict__ h2b,
        const unsigned short* __restrict__ Bt,
        const float* __restrict__ bl, const float* __restrict__ br,
        unsigned short* __restrict__ xc, int n) {
    __shared__ unsigned short Ash[32][264];
    __shared__ unsigned short Bsh[64][264];
    int t = threadIdx.x;
    int node0 = blockIdx.x * 32;
    for (int i = t; i < 32 * 32; i += 256) {
        int r = i >> 5, cs = i & 31;
        int nd = node0 + r;
        uint4 v = make_uint4(0u, 0u, 0u, 0u);
        if (nd < n) v = ((const uint4*)(h2b + (size_t)nd * 256))[cs];
        *(uint4*)&Ash[r][cs * 8] = v;
    }
    for (int i = t; i < 64 * 32; i += 256) {
        int r = i >> 5, cs = i & 31;
        uint4 v = ((const uint4*)(Bt + (size_t)r * 256))[cs];
        *(uint4*)&Bsh[r][cs * 8] = v;
    }
    __syncthreads();
    int wave = t >> 6, lane = t & 63;
    int m = lane & 15, q = lane >> 4;
    int mrow = (wave >> 1) * 16;
    int nh   = (wave & 1) * 32;
    f32x4 acc[2];
    acc[0] = (f32x4){0.f, 0.f, 0.f, 0.f};
    acc[1] = (f32x4){0.f, 0.f, 0.f, 0.f};
#pragma unroll
    for (int k = 0; k < 256; k += 32) {
        bf16x8 a = *(const bf16x8*)&Ash[mrow + m][k + q * 8];
#pragma unroll
        for (int nt = 0; nt < 2; ++nt) {
            bf16x8 b = *(const bf16x8*)&Bsh[nh + nt * 16 + m][k + q * 8];
            acc[nt] = __builtin_amdgcn_mfma_f32_16x16x32_bf16(a, b, acc[nt], 0, 0, 0);
        }
    }
#pragma unroll
    for (int r = 0; r < 4; ++r) {
        int node = node0 + mrow + q * 4 + r;
        if (node < n) {
#pragma unroll
            for (int nt = 0; nt < 2; ++nt) {
                int ng = nh + nt * 16 + m;
                float bvv = (ng < 32) ? bl[ng] : br[ng - 32];
                xc[(size_t)node * 64 + ng] = bf16r(acc[nt][r] + bvv);
            }
        }
    }
}

// ---------- GAT layer 1: wave/dst (128-thread blocks: less wave imbalance) ----------
__global__ __launch_bounds__(128) void k_gat256(const unsigned char* __restrict__ xl8,
        const unsigned short* __restrict__ xrp,
        const int* __restrict__ rowptrF, const int* __restrict__ packed,
        const float* __restrict__ eaWp, const float* __restrict__ loopWp,
        const float* __restrict__ attp, const float* __restrict__ biasp,
        const float* __restrict__ alpha, const float* __restrict__ delta,
        unsigned short* __restrict__ h2b, int n) {
    int wid = (blockIdx.x * blockDim.x + threadIdx.x) >> 6;
    if (wid >= n) return;
    int d = __builtin_amdgcn_readfirstlane(wid);
    int lane = threadIdx.x & 63;
    int c = lane * 4;
    const float S4 = 0.4f * L2E;
    f32x2 xldL, xldH;
    fp8dec(*(const unsigned int*)(xl8 + (size_t)d * 256 + c), xldL, xldH);
    uint2 uxr = ((const uint2*)(xrp + (size_t)d * 256))[lane];
    f32x2 xrdL, xrdH;
    xrdL.x = __uint_as_float(uxr.x << 16); xrdL.y = __uint_as_float(uxr.x & 0xFFFF0000u);
    xrdH.x = __uint_as_float(uxr.y << 16); xrdH.y = __uint_as_float(uxr.y & 0xFFFF0000u);
    f32x2 avL = *(const f32x2*)(attp + c), avH = *(const f32x2*)(attp + c + 2);
    f32x2 a4L = avL * sp2(S4), a4H = avH * sp2(S4);
    f32x2 gp = avL * xrdL + avH * xrdH;
    float gd = rflf(wsum64(gp.x + gp.y) * S6A);
    float ab0 = gd + delta[0], ab1 = gd + delta[1], ab2 = gd + delta[2];
    float ab3 = gd + delta[3];
    float alphad = alpha[d];
    f32x2 r0L = *(const f32x2*)(eaWp + c) + xrdL;
    f32x2 r0H = *(const f32x2*)(eaWp + c + 2) + xrdH;
    f32x2 r1L = *(const f32x2*)(eaWp + 256 + c) + xrdL;
    f32x2 r1H = *(const f32x2*)(eaWp + 256 + c + 2) + xrdH;
    f32x2 r2L = *(const f32x2*)(eaWp + 512 + c) + xrdL;
    f32x2 r2H = *(const f32x2*)(eaWp + 512 + c + 2) + xrdH;
    f32x2 lwL = *(const f32x2*)(loopWp + c) + xrdL;
    f32x2 lwH = *(const f32x2*)(loopWp + c + 2) + xrdH;
    int jj = lane & 15;
    int a0i = jj << 2, a1i = (jj + 16) << 2, a2i = (jj + 32) << 2, a3i = (jj + 48) << 2;
    bool bq0 = (lane & 16) != 0, bq1 = (lane & 32) != 0;
    float den;
    f32x2 accL, accH;
    {
        float q = wsum64(adot_pk(xldL, xldH, lwL, lwH, a4L, a4H)) + alphad + ab3;
        float wself = exp2f(q);
        den = wself;
        accL = xldL * sp2(wself);
        accH = xldH * sp2(wself);
    }
    int p = rowptrF[d * 3], p1 = rowptrF[d * 3 + 3];
    for (; p + 4 <= p1; p += 4) {
        int pk0 = packed[p],     pk1 = packed[p + 1];
        int pk2 = packed[p + 2], pk3 = packed[p + 3];
        int s0 = pk0 & 0xFFFF, s1 = pk1 & 0xFFFF;
        int s2 = pk2 & 0xFFFF, s3 = pk3 & 0xFFFF;
        int f0 = pk0 >> 16, f1 = pk1 >> 16, f2 = pk2 >> 16, f3 = pk3 >> 16;
        unsigned int g0 = *(const unsigned int*)(xl8 + (size_t)s0 * 256 + c);
        unsigned int g1 = *(const unsigned int*)(xl8 + (size_t)s1 * 256 + c);
        unsigned int g2 = *(const unsigned int*)(xl8 + (size_t)s2 * 256 + c);
        unsigned int g3 = *(const unsigned int*)(xl8 + (size_t)s3 * 256 + c);
        float sc0 = alpha[s0] + ((f0 == 0) ? ab0 : ((f0 == 1) ? ab1 : ab2));
        float sc1 = alpha[s1] + ((f1 == 0) ? ab0 : ((f1 == 1) ? ab1 : ab2));
        float sc2 = alpha[s2] + ((f2 == 0) ? ab0 : ((f2 == 1) ? ab1 : ab2));
        float sc3 = alpha[s3] + ((f3 == 0) ? ab0 : ((f3 == 1) ? ab1 : ab2));
        f32x2 x0L, x0H, x1L, x1H, x2L, x2H, x3L, x3H;
        fp8dec(g0, x0L, x0H); fp8dec(g1, x1L, x1H);
        fp8dec(g2, x2L, x2H); fp8dec(g3, x3L, x3H);
        float q0, q1, q2, q3;
        if (f0 == f3) {
            f32x2 pL = (f0 == 0) ? r0L : ((f0 == 1) ? r1L : r2L);
            f32x2 pH = (f0 == 0) ? r0H : ((f0 == 1) ? r1H : r2H);
            q0 = adot_pk(x0L, x0H, pL, pH, a4L, a4H);
            q1 = adot_pk(x1L, x1H, pL, pH, a4L, a4H);
            q2 = adot_pk(x2L, x2H, pL, pH, a4L, a4H);
            q3 = adot_pk(x3L, x3H, pL, pH, a4L, a4H);
        } else {
            f32x2 p0L = (f0 == 0) ? r0L : ((f0 == 1) ? r1L : r2L);
            f32x2 p0H = (f0 == 0) ? r0H : ((f0 == 1) ? r1H : r2H);
            f32x2 p1L_ = (f1 == 0) ? r0L : ((f1 == 1) ? r1L : r2L);
            f32x2 p1H_ = (f1 == 0) ? r0H : ((f1 == 1) ? r1H : r2H);
            f32x2 p2L = (f2 == 0) ? r0L : ((f2 == 1) ? r1L : r2L);
            f32x2 p2H = (f2 == 0) ? r0H : ((f2 == 1) ? r1H : r2H);
            f32x2 p3L = (f3 == 0) ? r0L : ((f3 == 1) ? r1L : r2L);
            f32x2 p3H = (f3 == 0) ? r0H : ((f3 == 1) ? r1H : r2H);
            q0 = adot_pk(x0L, x0H, p0L, p0H, a4L, a4H);
            q1 = adot_pk(x1L, x1H, p1L_, p1H_, a4L, a4H);
            q2 = adot_pk(x2L, x2H, p2L, p2H, a4L, a4H);
            q3 = adot_pk(x3L, x3H, p3L, p3H, a4L, a4H);
        }
        q0 += __shfl_xor(q0, 16, 64); q1 += __shfl_xor(q1, 16, 64);
        q2 += __shfl_xor(q2, 16, 64); q3 += __shfl_xor(q3, 16, 64);
        q0 += __shfl_xor(q0, 32, 64); q1 += __shfl_xor(q1, 32, 64);
        q2 += __shfl_xor(q2, 32, 64); q3 += __shfl_xor(q3, 32, 64);
        float r01 = bq0 ? q1 : q0, r23 = bq0 ? q3 : q2;
        float rr = bq1 ? r23 : r01;
        rr += __shfl_xor(rr, 1, 64); rr += __shfl_xor(rr, 2, 64);
        rr += __shfl_xor(rr, 4, 64); rr += __shfl_xor(rr, 8, 64);
        float s01 = bq0 ? sc1 : sc0, s23 = bq0 ? sc3 : sc2;
        float scv = bq1 ? s23 : s01;
        float w = exp2f(rr + scv);
        int wi = __float_as_int(w);
        float w0 = __int_as_float(__builtin_amdgcn_ds_bpermute(a0i, wi));
        float w1 = __int_as_float(__builtin_amdgcn_ds_bpermute(a1i, wi));
        float w2 = __int_as_float(__builtin_amdgcn_ds_bpermute(a2i, wi));
        float w3 = __int_as_float(__builtin_amdgcn_ds_bpermute(a3i, wi));
        den += (w0 + w1) + (w2 + w3);
        accL += x0L * sp2(w0) + x1L * sp2(w1) + x2L * sp2(w2) + x3L * sp2(w3);
        accH += x0H * sp2(w0) + x1H * sp2(w1) + x2H * sp2(w2) + x3H * sp2(w3);
    }
    for (; p < p1; ++p) {
        int pk = packed[p];
        int s = pk & 0xFFFF, f = pk >> 16;
        unsigned int g = *(const unsigned int*)(xl8 + (size_t)s * 256 + c);
        float sc = alpha[s] + ((f == 0) ? ab0 : ((f == 1) ? ab1 : ab2));
        f32x2 xL, xH;
        fp8dec(g, xL, xH);
        f32x2 pL = (f == 0) ? r0L : ((f == 1) ? r1L : r2L);
        f32x2 pH = (f == 0) ? r0H : ((f == 1) ? r1H : r2H);
        float q = wsum64(adot_pk(xL, xH, pL, pH, a4L, a4H)) + sc;
        float w = exp2f(q);
        den += w;
        accL += xL * sp2(w);
        accH += xH * sp2(w);
    }
    float inv = 1.f / den;
    f32x2 bvL = *(const f32x2*)(biasp + c), bvH = *(const f32x2*)(biasp + c + 2);
    f32x2 oL = accL * sp2(inv) + bvL;
    f32x2 oH = accH * sp2(inv) + bvH;
    ((uint2*)(h2b + (size_t)d * 256))[lane] =
        make_uint2(bf16pack(oL.x, oL.y), bf16pack(oH.x, oH.y));
}

// ---------- GAT layer 2: wave/dst (256-thread blocks), 4 groups x 16 lanes x 2 dims ----------
__global__ __launch_bounds__(256) void k_gat32(const unsigned short* __restrict__ xc2,
        const int* __restrict__ rowptrF, const int* __restrict__ packed,
        const float* __restrict__ eaW, const float* __restrict__ loopW,
        const float* __restrict__ att, const float* __restrict__ bias,
        float* __restrict__ out, int n) {
    int wid = (blockIdx.x * blockDim.x + threadIdx.x) >> 6;
    if (wid >= n) return;
    int d = __builtin_amdgcn_readfirstlane(wid);
    int lane = threadIdx.x & 63;
    int g = lane >> 4, li = lane & 15;
    unsigned int uxl = ((const unsigned int*)(xc2 + (size_t)d * 64))[li];
    unsigned int uxr = ((const unsigned int*)(xc2 + (size_t)d * 64 + 32))[li];
    float xl0 = __uint_as_float(uxl << 16), xl1 = __uint_as_float(uxl & 0xFFFF0000u);
    float xr0 = __uint_as_float(uxr << 16), xr1 = __uint_as_float(uxr & 0xFFFF0000u);
    float2 avv = ((const float2*)att)[li];
    float a60 = 0.6f * L2E * avv.x, a61 = 0.6f * L2E * avv.y;
    float a40 = 0.4f * L2E * avv.x, a41 = 0.4f * L2E * avv.y;
    float2 e0 = ((const float2*)eaW)[li];
    float2 e1 = ((const float2*)(eaW + 32))[li];
    float2 e2 = ((const float2*)(eaW + 64))[li];
    float p00 = e0.x + xr0, p01 = e0.y + xr1;
    float p10 = e1.x + xr0, p11 = e1.y + xr1;
    float p20 = e2.x + xr0, p21 = e2.y + xr1;
    float den, acc0, acc1;
    {
        float2 lwv = ((const float2*)loopW)[li];
        float m0 = xl0 + xr0 + lwv.x, m1 = xl1 + xr1 + lwv.y;
        float q = a60 * m0 + a40 * fabsf(m0);
        q = fmaf(a61, m1, q); q = fmaf(a41, fabsf(m1), q);
        q += __shfl_xor(q, 1, 64); q += __shfl_xor(q, 2, 64);
        q += __shfl_xor(q, 4, 64); q += __shfl_xor(q, 8, 64);
        float wself = exp2f(q);
        den  = (g == 0) ? wself : 0.f;
        acc0 = (g == 0) ? wself * xl0 : 0.f;
        acc1 = (g == 0) ? wself * xl1 : 0.f;
    }
    int pA = rowptrF[d * 3], pB = rowptrF[d * 3 + 3];
    int p = pA + g;
    for (; p + 12 < pB; p += 16) {
        int pkA = packed[p], pkB = packed[p + 4];
        int pkC = packed[p + 8], pkD = packed[p + 12];
        unsigned int ua = ((const unsigned int*)(xc2 + (size_t)(pkA & 0xFFFF) * 64))[li];
        unsigned int ub = ((const unsigned int*)(xc2 + (size_t)(pkB & 0xFFFF) * 64))[li];
        unsigned int uc = ((const unsigned int*)(xc2 + (size_t)(pkC & 0xFFFF) * 64))[li];
        unsigned int ud = ((const unsigned int*)(xc2 + (size_t)(pkD & 0xFFFF) * 64))[li];
        int fA = pkA >> 16, fB = pkB >> 16, fC = pkC >> 16, fD = pkD >> 16;
        float prA0 = (fA == 0) ? p00 : ((fA == 1) ? p10 : p20);
        float prA1 = (fA == 0) ? p01 : ((fA == 1) ? p11 : p21);
        float prB0 = (fB == 0) ? p00 : ((fB == 1) ? p10 : p20);
        float prB1 = (fB == 0) ? p01 : ((fB == 1) ? p11 : p21);
        float prC0 = (fC == 0) ? p00 : ((fC == 1) ? p10 : p20);
        float prC1 = (fC == 0) ? p01 : ((fC == 1) ? p11 : p21);
        float prD0 = (fD == 0) ? p00 : ((fD == 1) ? p10 : p20);
        float prD1 = (fD == 0) ? p01 : ((fD == 1) ? p11 : p21);
        float xa0 = __uint_as_float(ua << 16), xa1 = __uint_as_float(ua & 0xFFFF0000u);
        float xb0 = __uint_as_float(ub << 16), xb1 = __uint_as_float(ub & 0xFFFF0000u);
        float xcc0 = __uint_as_float(uc << 16), xcc1 = __uint_as_float(uc & 0xFFFF0000u);
        float xd0 = __uint_as_float(ud << 16), xd1 = __uint_as_float(ud & 0xFFFF0000u);
        float ma0 = xa0 + prA0, ma1 = xa1 + prA1;
        float mb0 = xb0 + prB0, mb1 = xb1 + prB1;
        float mc0 = xcc0 + prC0, mc1 = xcc1 + prC1;
        float md0 = xd0 + prD0, md1 = xd1 + prD1;
        float qa = a60 * ma0 + a40 * fabsf(ma0);
        qa = fmaf(a61, ma1, qa); qa = fmaf(a41, fabsf(ma1), qa);
        float qb = a60 * mb0 + a40 * fabsf(mb0);
        qb = fmaf(a61, mb1, qb); qb = fmaf(a41, fabsf(mb1), qb);
        float qc = a60 * mc0 + a40 * fabsf(mc0);
        qc = fmaf(a61, mc1, qc); qc = fmaf(a41, fabsf(mc1), qc);
        float qd = a60 * md0 + a40 * fabsf(md0);
        qd = fmaf(a61, md1, qd); qd = fmaf(a41, fabsf(md1), qd);
#pragma unroll
        for (int off = 1; off <= 8; off <<= 1) {
            qa += __shfl_xor(qa, off, 64);
            qb += __shfl_xor(qb, off, 64);
            qc += __shfl_xor(qc, off, 64);
            qd += __shfl_xor(qd, off, 64);
        }
        float wa = exp2f(qa), wb = exp2f(qb);
        float wc = exp2f(qc), wd = exp2f(qd);
        den += (wa + wb) + (wc + wd);
        acc0 += wa * xa0 + wb * xb0 + wc * xcc0 + wd * xd0;
        acc1 += wa * xa1 + wb * xb1 + wc * xcc1 + wd * xd1;
    }
    for (; p + 4 < pB; p += 8) {
        int pkA = packed[p], pkB = packed[p + 4];
        unsigned int ua = ((const unsigned int*)(xc2 + (size_t)(pkA & 0xFFFF) * 64))[li];
        unsigned int ub = ((const unsigned int*)(xc2 + (size_t)(pkB & 0xFFFF) * 64))[li];
        int fA = pkA >> 16, fB = pkB >> 16;
        float prA0 = (fA == 0) ? p00 : ((fA == 1) ? p10 : p20);
        float prA1 = (fA == 0) ? p01 : ((fA == 1) ? p11 : p21);
        float prB0 = (fB == 0) ? p00 : ((fB == 1) ? p10 : p20);
        float prB1 = (fB == 0) ? p01 : ((fB == 1) ? p11 : p21);
        float xa0 = __uint_as_float(ua << 16), xa1 = __uint_as_float(ua & 0xFFFF0000u);
        float xb0 = __uint_as_float(ub << 16), xb1 = __uint_as_float(ub & 0xFFFF0000u);
        float ma0 = xa0 + prA0, ma1 = xa1 + prA1;
        float mb0 = xb0 + prB0, mb1 = xb1 + prB1;
        float qa = a60 * ma0 + a40 * fabsf(ma0);
        qa = fmaf(a61, ma1, qa); qa = fmaf(a41, fabsf(ma1), qa);
        float qb = a60 * mb0 + a40 * fabsf(mb0);
        qb = fmaf(a61, mb1, qb); qb = fmaf(a41, fabsf(mb1), qb);
#pragma unroll
        for (int off = 1; off <= 8; off <<= 1) {
            qa += __shfl_xor(qa, off, 64);
            qb += __shfl_xor(qb, off, 64);
        }
        float wa = exp2f(qa), wb = exp2f(qb);
        den += wa + wb;
        acc0 += wa * xa0 + wb * xb0;
        acc1 += wa * xa1 + wb * xb1;
    }
    for (; p < pB; p += 4) {
        int pk = packed[p];
        unsigned int u = ((const unsigned int*)(xc2 + (size_t)(pk & 0xFFFF) * 64))[li];
        int f = pk >> 16;
        float pre0 = (f == 0) ? p00 : ((f == 1) ? p10 : p20);
        float pre1 = (f == 0) ? p01 : ((f == 1) ? p11 : p21);
        float x0 = __uint_as_float(u << 16), x1 = __uint_as_float(u & 0xFFFF0000u);
        float m0 = x0 + pre0, m1 = x1 + pre1;
        float q = a60 * m0 + a40 * fabsf(m0);
        q = fmaf(a61, m1, q); q = fmaf(a41, fabsf(m1), q);
        q += __shfl_xor(q, 1, 64); q += __shfl_xor(q, 2, 64);
        q += __shfl_xor(q, 4, 64); q += __shfl_xor(q, 8, 64);
        float w = exp2f(q);
        den += w;
        acc0 = fmaf(w, x0, acc0);
        acc1 = fmaf(w, x1, acc1);
    }
    acc0 += __shfl_xor(acc0, 16, 64); acc0 += __shfl_xor(acc0, 32, 64);
    acc1 += __shfl_xor(acc1, 16, 64); acc1 += __shfl_xor(acc1, 32, 64);
    den  += __shfl_xor(den, 16, 64);  den  += __shfl_xor(den, 32, 64);
    if (g == 0) {
        float2 bvv = ((const float2*)bias)[li];
        float inv = 1.f / den;
        float2 o;
        o.x = fmaf(acc0, inv, bvv.x);
        o.y = fmaf(acc1, inv, bvv.y);
        ((float2*)(out + (size_t)d * 32))[li] = o;
    }
}

// ---------- fused mean + policy head (last block finalizes) ----------
__global__ __launch_bounds__(256) void k_tail(const float* __restrict__ out2,
        float* __restrict__ gsum, int* __restrict__ done,
        const float* __restrict__ policy_W, const float* __restrict__ policy_b,
        float* __restrict__ out, int n) {
    __shared__ float sh[256];
    __shared__ int lastFlag;
    int t = threadIdx.x;
    int c = t & 31, g = t >> 5;
    float acc = 0.f;
    for (int nd = blockIdx.x * 8 + g; nd < n; nd += gridDim.x * 8)
        acc += out2[(size_t)nd * 32 + c];
    sh[t] = acc;
    __syncthreads();
    if (t < 32) {
        float s2 = 0.f;
#pragma unroll
        for (int gg = 0; gg < 8; ++gg) s2 += sh[gg * 32 + c];
        atomicAdd(&gsum[c], s2);
    }
    __syncthreads();
    if (t == 0) {
        __threadfence();
        int old = atomicAdd(done, 1);
        lastFlag = (old == (int)gridDim.x - 1) ? 1 : 0;
    }
    __syncthreads();
    if (lastFlag) {
        if (t < 32) sh[t] = atomicAdd(&gsum[t], 0.f);
        __syncthreads();
        if (t < 64) {
            float invN = 1.0f / (float)n;
            float a = policy_b[t];
            for (int cc = 0; cc < 32; ++cc) a += sh[cc] * invN * policy_W[cc * 64 + t];
            float mx = wmax64(a);
            float ex = __expf(a - mx);
            float s = wsum64(ex);
            out[t] = ex / s;
        }
    }
}

extern "C" void kernel_launch(void* const* d_in, const int* in_sizes, int n_in,
                              void* d_out, int out_size, void* d_ws, size_t ws_size,
                              hipStream_t stream) {
    const int* x          = (const int*)d_in[0];
    const int* edge_index = (const int*)d_in[1];
    const int* edge_attr  = (const int*)d_in[2];
    const float* text_emb = (const float*)d_in[3];
    const float* type_emb = (const float*)d_in[4];
    const float* flow_emb = (const float*)d_in[5];
    const float* pos_table= (const float*)d_in[6];
    const float* pos_W    = (const float*)d_in[7];
    const float* pos_b    = (const float*)d_in[8];
    const float* c1_Wl    = (const float*)d_in[9];
    const float* c1_bl    = (const float*)d_in[10];
    const float* c1_Wr    = (const float*)d_in[11];
    const float* c1_br    = (const float*)d_in[12];
    const float* c1_We    = (const float*)d_in[13];
    const float* c1_att   = (const float*)d_in[14];
    const float* c1_bias  = (const float*)d_in[15];
    const float* c2_Wl    = (const float*)d_in[16];
    const float* c2_bl    = (const float*)d_in[17];
    const float* c2_Wr    = (const float*)d_in[18];
    const float* c2_br    = (const float*)d_in[19];
    const float* c2_We    = (const float*)d_in[20];
    const float* c2_att   = (const float*)d_in[21];
    const float* c2_bias  = (const float*)d_in[22];
    const float* policy_W = (const float*)d_in[23];
    const float* policy_b = (const float*)d_in[24];
    float* out = (float*)d_out;

    const int N = in_sizes[0] / 2;   // 50000
    const int E = in_sizes[1] / 2;   // 800000
    const int n3 = 3 * N;

    char* base = (char*)d_ws;
    size_t off = 0;
    auto alloc = [&](size_t bytes) -> void* {
        void* p = base + off;
        off = (off + bytes + 255) & ~(size_t)255;
        return p;
    };
    unsigned char*  xl8  = (unsigned char*)alloc((size_t)N * 256);
    unsigned short* xrp  = (unsigned short*)alloc((size_t)N * 256 * 2);
    unsigned short* h2b  = (unsigned short*)alloc((size_t)N * 256 * 2);
    unsigned short* xc2  = (unsigned short*)alloc((size_t)N * 64 * 2);
    float*          out2 = (float*)alloc((size_t)N * 32 * 4);
    unsigned short* Bt1  = (unsigned short*)alloc((size_t)512 * 128 * 2);
    unsigned short* Bt2  = (unsigned short*)alloc((size_t)64 * 256 * 2);
    // zero-region: cntF (3N) | cnt3 (4) | gsum (32) | done (4) | alpha (N)
    int*            zreg   = (int*)alloc((size_t)(n3 + 40 + N) * 4);
    int*            cntF   = zreg;
    int*            cnt3   = zreg + n3;
    float*          gsum   = (float*)(zreg + n3 + 4);
    int*            done   = zreg + n3 + 36;
    float*          alpha1 = (float*)(zreg + n3 + 40);
    int*            rowptrF= (int*)alloc((size_t)(n3 + 1) * 4);
    int*            packed = (int*)alloc((size_t)E * 4);
    int*            bsum   = (int*)alloc(256 * 4);
    float*          delta1 = (float*)alloc(4 * 4);
    float*          eaW1p  = (float*)alloc(768 * 4);
    float*          loopW1p= (float*)alloc(256 * 4);
    float*          att1p  = (float*)alloc(256 * 4);
    float*          bias1p = (float*)alloc(256 * 4);
    float*          eaW2   = (float*)alloc(96 * 4);
    float*          loopW2 = (float*)alloc(32 * 4);
    float*          poscS  = (float*)alloc(128 * 4);

    hipMemsetAsync(zreg, 0, (size_t)(n3 + 40 + N) * 4, stream);

    const int EB = (E + 255) / 256;
    k_edges_prep<<<EB + 320 + 1, 256, 0, stream>>>(
        edge_index, edge_attr, cntF, cnt3, E, EB,
        pos_table, pos_W, pos_b, flow_emb, c1_We, c2_We, c1_att, c1_bias,
        eaW1p, att1p, bias1p, eaW2, delta1, poscS,
        c1_Wl, c1_Wr, c2_Wl, c2_Wr, Bt1, Bt2);

    int nb = (n3 + 1023) / 1024;
    k_scan_block<<<nb + 1, 256, 0, stream>>>(cntF, rowptrF, bsum, n3, nb,
        cnt3, poscS, flow_emb, c1_We, c2_We, c1_att, loopW1p, loopW2, delta1, E);

    k_scan_add<<<(n3 + 255) / 256, 256, 0, stream>>>(rowptrF, bsum, cntF, n3, nb);

    k_scatter<<<EB, 256, 0, stream>>>(edge_index, edge_attr, cntF, packed, E);

    k_gemm1<<<(N + 63) / 64, 256, 0, stream>>>(x, text_emb, type_emb, Bt1,
                                               c1_bl, c1_br, c1_att, alpha1, xl8, xrp, N);

    k_gat256<<<(N + 1) / 2, 128, 0, stream>>>(xl8, xrp, rowptrF, packed, eaW1p, loopW1p,
                                              att1p, bias1p, alpha1, delta1, h2b, N);

    k_gemm2<<<(N + 31) / 32, 256, 0, stream>>>(h2b, Bt2, c2_bl, c2_br, xc2, N);

    k_gat32<<<(N + 3) / 4, 256, 0, stream>>>(xc2, rowptrF, packed, eaW2, loopW2,
                                             c2_att, c2_bias, out2, N);

    k_tail<<<256, 256, 0, stream>>>(out2, gsum, done, policy_W, policy_b, out, N);
}